// Round 2
// baseline (5603.445 us; speedup 1.0000x reference)
//
#include <hip/hip_runtime.h>

#define NP 4  // nodes per wave in the dense per-node kernels

// ---------------- node MLP: feature attention + projection ----------------
// fw = sigmoid(relu(x@faW1+b1)@faW2+b2); h = (x*fw)@projW + projb
// 4 nodes per wave: each weight load feeds 8 FMAs, 4 independent chains.
__global__ void k_mlp(const float* __restrict__ x,
                      const float* __restrict__ faW1, const float* __restrict__ fab1,
                      const float* __restrict__ faW2, const float* __restrict__ fab2,
                      const float* __restrict__ projW, const float* __restrict__ projb,
                      float* __restrict__ hbuf, int N) {
    int w    = (blockIdx.x * blockDim.x + threadIdx.x) >> 6;
    int lane = threadIdx.x & 63;
    int n0 = w * NP;
    if (n0 >= N) return;

    float x0[NP], x1[NP];
#pragma unroll
    for (int k = 0; k < NP; ++k) {
        int n = n0 + k < N ? n0 + k : N - 1;
        x0[k] = x[(size_t)n * 128 + lane];
        x1[k] = x[(size_t)n * 128 + 64 + lane];
    }

    // t = relu(x @ faW1 + b1)   [64]
    float t[NP];
#pragma unroll
    for (int k = 0; k < NP; ++k) t[k] = fab1[lane];
#pragma unroll
    for (int i = 0; i < 64; ++i) {
        float w0 = faW1[i * 64 + lane];
        float w1 = faW1[(64 + i) * 64 + lane];
#pragma unroll
        for (int k = 0; k < NP; ++k) {
            t[k] = fmaf(__shfl(x0[k], i, 64), w0, t[k]);
            t[k] = fmaf(__shfl(x1[k], i, 64), w1, t[k]);
        }
    }
#pragma unroll
    for (int k = 0; k < NP; ++k) t[k] = fmaxf(t[k], 0.f);

    // f = t @ faW2 + b2  [128]; lane holds j=lane and j=64+lane
    float f0[NP], f1[NP];
#pragma unroll
    for (int k = 0; k < NP; ++k) { f0[k] = fab2[lane]; f1[k] = fab2[64 + lane]; }
#pragma unroll
    for (int j = 0; j < 64; ++j) {
        float w0 = faW2[j * 128 + lane];
        float w1 = faW2[j * 128 + 64 + lane];
#pragma unroll
        for (int k = 0; k < NP; ++k) {
            float tj = __shfl(t[k], j, 64);
            f0[k] = fmaf(tj, w0, f0[k]);
            f1[k] = fmaf(tj, w1, f1[k]);
        }
    }
    // xm = x * sigmoid(f)
#pragma unroll
    for (int k = 0; k < NP; ++k) {
        f0[k] = x0[k] / (1.f + __expf(-f0[k]));
        f1[k] = x1[k] / (1.f + __expf(-f1[k]));
    }

    // h = xm @ projW + projb  [64]
    float h[NP];
#pragma unroll
    for (int k = 0; k < NP; ++k) h[k] = projb[lane];
#pragma unroll
    for (int i = 0; i < 64; ++i) {
        float w0 = projW[i * 64 + lane];
        float w1 = projW[(64 + i) * 64 + lane];
#pragma unroll
        for (int k = 0; k < NP; ++k) {
            h[k] = fmaf(__shfl(f0[k], i, 64), w0, h[k]);
            h[k] = fmaf(__shfl(f1[k], i, 64), w1, h[k]);
        }
    }
#pragma unroll
    for (int k = 0; k < NP; ++k)
        if (n0 + k < N) hbuf[(size_t)(n0 + k) * 64 + lane] = h[k];
}

// ---------------- GAT: z = h@W, es = z.asrc, ed = z.adst ----------------
__global__ void k_z(const float* __restrict__ hbuf, const float* __restrict__ W,
                    const float* __restrict__ asrc, const float* __restrict__ adst,
                    float* __restrict__ zbuf, float* __restrict__ es, float* __restrict__ ed,
                    int N) {
    int w    = (blockIdx.x * blockDim.x + threadIdx.x) >> 6;
    int lane = threadIdx.x & 63;
    int n0 = w * NP;
    if (n0 >= N) return;

    float h[NP];
#pragma unroll
    for (int k = 0; k < NP; ++k) {
        int n = n0 + k < N ? n0 + k : N - 1;
        h[k] = hbuf[(size_t)n * 64 + lane];
    }
    float z[NP];
#pragma unroll
    for (int k = 0; k < NP; ++k) z[k] = 0.f;
#pragma unroll
    for (int i = 0; i < 64; ++i) {
        float wv = W[i * 64 + lane];
#pragma unroll
        for (int k = 0; k < NP; ++k)
            z[k] = fmaf(__shfl(h[k], i, 64), wv, z[k]);
    }
    float as = asrc[lane], ad = adst[lane];
    float vs[NP], vd[NP];
#pragma unroll
    for (int k = 0; k < NP; ++k) { vs[k] = z[k] * as; vd[k] = z[k] * ad; }
#pragma unroll
    for (int off = 32; off; off >>= 1) {
#pragma unroll
        for (int k = 0; k < NP; ++k) {
            vs[k] += __shfl_xor(vs[k], off, 64);
            vd[k] += __shfl_xor(vd[k], off, 64);
        }
    }
#pragma unroll
    for (int k = 0; k < NP; ++k)
        if (n0 + k < N) zbuf[(size_t)(n0 + k) * 64 + lane] = z[k];
    if (lane == 0) {
#pragma unroll
        for (int k = 0; k < NP; ++k)
            if (n0 + k < N) { es[n0 + k] = vs[k]; ed[n0 + k] = vd[k]; }
    }
}

// ---------------- CSR build (dst-grouped, self-loops appended) ----------------
__global__ void k_hist(const int* __restrict__ ei, int E, int Etot, int* __restrict__ cnt) {
    int i = blockIdx.x * blockDim.x + threadIdx.x;
    if (i >= Etot) return;
    int d = i < E ? ei[E + i] : i - E;
    atomicAdd(&cnt[d], 1);
}

// per-wave exclusive scan + single bump-alloc atomic per wave
__global__ void k_alloc(const int* __restrict__ cnt, int* __restrict__ start,
                        int* __restrict__ gcur, int N) {
    int idx  = blockIdx.x * blockDim.x + threadIdx.x;
    int lane = threadIdx.x & 63;
    int c = idx < N ? cnt[idx] : 0;
    int sc = c;
#pragma unroll
    for (int off = 1; off < 64; off <<= 1) {
        int t = __shfl_up(sc, off, 64);
        if (lane >= off) sc += t;
    }
    int base = 0;
    if (lane == 63) base = atomicAdd(gcur, sc);
    base = __shfl(base, 63, 64);
    if (idx < N) start[idx] = base + sc - c;
}

__global__ void k_fill(const int* __restrict__ ei, int E, int Etot,
                       const int* __restrict__ start, int* __restrict__ cursor,
                       int* __restrict__ esrc) {
    int i = blockIdx.x * blockDim.x + threadIdx.x;
    if (i >= Etot) return;
    int s, d;
    if (i < E) { s = ei[i]; d = ei[E + i]; } else { s = d = i - E; }
    int p = atomicAdd(&cursor[d], 1);
    esrc[start[d] + p] = s;
}

// ---------------- fused GAT aggregation: softmax + scatter + bias + BN + ReLU ----
// one wave per dst node; lane = feature. No float atomics anywhere.
__global__ void k_agg(const int* __restrict__ start, const int* __restrict__ cnt,
                      const int* __restrict__ esrc,
                      const float* __restrict__ es, const float* __restrict__ ed,
                      const float* __restrict__ zbuf,
                      const float* __restrict__ b, const float* __restrict__ g,
                      const float* __restrict__ bta, const float* __restrict__ mean,
                      const float* __restrict__ var,
                      float* __restrict__ hbuf, int N) {
    int wid  = (blockIdx.x * blockDim.x + threadIdx.x) >> 6;
    int lane = threadIdx.x & 63;
    if (wid >= N) return;
    int row0 = start[wid];
    int c    = cnt[wid];          // >= 1 (self-loop)
    float edn = ed[wid];

    // phase A: segment max (lanes parallel over edges)
    float m = -1e30f;
    for (int k = lane; k < c; k += 64) {
        float e = es[esrc[row0 + k]] + edn;
        e = e >= 0.f ? e : 0.2f * e;
        m = fmaxf(m, e);
    }
#pragma unroll
    for (int off = 32; off; off >>= 1) m = fmaxf(m, __shfl_xor(m, off, 64));

    // phase B: denom
    float ssum = 0.f;
    for (int k = lane; k < c; k += 64) {
        float e = es[esrc[row0 + k]] + edn;
        e = e >= 0.f ? e : 0.2f * e;
        ssum += __expf(e - m);
    }
#pragma unroll
    for (int off = 32; off; off >>= 1) ssum += __shfl_xor(ssum, off, 64);

    // phase C: acc = sum z[src]*exp(e-m), software-pipelined gather
    float acc = 0.f;
    int   s  = esrc[row0];
    float zv = zbuf[(size_t)s * 64 + lane];
    float ep = es[s] + edn; ep = ep >= 0.f ? ep : 0.2f * ep;
    for (int k = 1; k < c; ++k) {
        int   s1 = esrc[row0 + k];
        float zn = zbuf[(size_t)s1 * 64 + lane];
        float en = es[s1] + edn; en = en >= 0.f ? en : 0.2f * en;
        acc = fmaf(zv, __expf(ep - m), acc);
        zv = zn; ep = en;
    }
    acc = fmaf(zv, __expf(ep - m), acc);
    acc /= ssum;

    // epilogue: +bias, BN(eval), ReLU
    float sc = g[lane] * rsqrtf(var[lane] + 1e-5f);
    float v  = (acc + b[lane] - mean[lane]) * sc + bta[lane];
    hbuf[(size_t)wid * 64 + lane] = fmaxf(v, 0.f);
}

// ---------------- structural ----------------
__global__ void k_deg(const int* __restrict__ ei, int E, float* __restrict__ deg) {
    int e = blockIdx.x * blockDim.x + threadIdx.x;
    if (e < E) atomicAdd(&deg[ei[e]], 1.f);
}
__global__ void k_inflsum(const int* __restrict__ ei, int E,
                          const float* __restrict__ deg, float* __restrict__ inflsum) {
    int e = blockIdx.x * blockDim.x + threadIdx.x;
    if (e < E) atomicAdd(&inflsum[ei[e]], deg[ei[E + e]]);
}
__global__ void k_infl(const float* __restrict__ deg, const float* __restrict__ inflsum,
                       float* __restrict__ inflv, unsigned* __restrict__ scal, int N) {
    int idx = blockIdx.x * blockDim.x + threadIdx.x;
    float d = 0.f, iv = 0.f;
    if (idx < N) {
        d = deg[idx];
        iv = d > 0.f ? inflsum[idx] / d : 0.f;
        inflv[idx] = iv;
    }
    float dm = d, im = iv;
#pragma unroll
    for (int off = 32; off; off >>= 1) {
        dm = fmaxf(dm, __shfl_xor(dm, off, 64));
        im = fmaxf(im, __shfl_xor(im, off, 64));
    }
    if ((threadIdx.x & 63) == 0) {
        atomicMax(scal + 0, __float_as_uint(dm));   // non-negative: bits order-preserving
        atomicMax(scal + 1, __float_as_uint(im));
    }
}

// ---------------- structural MLP + concat + output MLP (4 nodes/wave) --------
__global__ void k_final(const float* __restrict__ hbuf, const float* __restrict__ deg,
                        const float* __restrict__ inflv, const unsigned* __restrict__ scal,
                        const float* __restrict__ seW1, const float* __restrict__ seb1,
                        const float* __restrict__ seW2, const float* __restrict__ seb2,
                        const float* __restrict__ oW1, const float* __restrict__ ob1,
                        const float* __restrict__ oW2, const float* __restrict__ ob2,
                        const float* __restrict__ oW3, const float* __restrict__ ob3,
                        float* __restrict__ out, int N) {
    int w    = (blockIdx.x * blockDim.x + threadIdx.x) >> 6;
    int lane = threadIdx.x & 63;
    int n0 = w * NP;
    if (n0 >= N) return;
    int lk = lane & 31;

    float degmax  = fmaxf(__uint_as_float(scal[0]), 1.0f);
    float inflmax = fmaxf(__uint_as_float(scal[1]), 1e-12f);

    float h[NP], hid[NP];
#pragma unroll
    for (int k = 0; k < NP; ++k) {
        int n = n0 + k < N ? n0 + k : N - 1;
        h[k] = hbuf[(size_t)n * 64 + lane];
        float nd = deg[n] / degmax;
        float fl = inflv[n] / inflmax;
        hid[k] = fmaxf(nd * seW1[lk] + fl * seW1[64 + lk] + seb1[lk], 0.f);
    }

    // se = hidden @ seW2 + seb2   [64]
    float se[NP];
#pragma unroll
    for (int k = 0; k < NP; ++k) se[k] = seb2[lane];
#pragma unroll
    for (int j = 0; j < 32; ++j) {
        float wv = seW2[j * 64 + lane];
#pragma unroll
        for (int k = 0; k < NP; ++k)
            se[k] = fmaf(__shfl(hid[k], j, 64), wv, se[k]);
    }

    // o1 = relu([h, se] @ oW1 + ob1)  [64]
    float o1[NP];
#pragma unroll
    for (int k = 0; k < NP; ++k) o1[k] = ob1[lane];
#pragma unroll
    for (int i = 0; i < 64; ++i) {
        float w0 = oW1[i * 64 + lane];
        float w1 = oW1[(64 + i) * 64 + lane];
#pragma unroll
        for (int k = 0; k < NP; ++k) {
            o1[k] = fmaf(__shfl(h[k], i, 64),  w0, o1[k]);
            o1[k] = fmaf(__shfl(se[k], i, 64), w1, o1[k]);
        }
    }
#pragma unroll
    for (int k = 0; k < NP; ++k) o1[k] = fmaxf(o1[k], 0.f);

    // o2 = relu(o1 @ oW2 + ob2)  [32] (upper 32 lanes duplicate)
    float o2[NP];
#pragma unroll
    for (int k = 0; k < NP; ++k) o2[k] = ob2[lk];
#pragma unroll
    for (int j = 0; j < 64; ++j) {
        float wv = oW2[j * 32 + lk];
#pragma unroll
        for (int k = 0; k < NP; ++k)
            o2[k] = fmaf(__shfl(o1[k], j, 64), wv, o2[k]);
    }

    // out = sigmoid(o2 @ oW3 + ob3)
    float cacc[NP];
#pragma unroll
    for (int k = 0; k < NP; ++k) {
        o2[k] = fmaxf(o2[k], 0.f);
        cacc[k] = (lane < 32) ? o2[k] * oW3[lk] : 0.f;
    }
#pragma unroll
    for (int off = 32; off; off >>= 1)
#pragma unroll
        for (int k = 0; k < NP; ++k) cacc[k] += __shfl_xor(cacc[k], off, 64);
    if (lane == 0) {
#pragma unroll
        for (int k = 0; k < NP; ++k)
            if (n0 + k < N) out[n0 + k] = 1.f / (1.f + __expf(-(cacc[k] + ob3[0])));
    }
}

// ---------------- launch ----------------
extern "C" void kernel_launch(void* const* d_in, const int* in_sizes, int n_in,
                              void* d_out, int out_size, void* d_ws, size_t ws_size,
                              hipStream_t stream) {
    const float* x     = (const float*)d_in[0];
    const int*   ei    = (const int*)d_in[1];
    const float* faW1  = (const float*)d_in[2];
    const float* fab1  = (const float*)d_in[3];
    const float* faW2  = (const float*)d_in[4];
    const float* fab2  = (const float*)d_in[5];
    const float* projW = (const float*)d_in[6];
    const float* projb = (const float*)d_in[7];
    const float* gatW  = (const float*)d_in[8];
    const float* gatAs = (const float*)d_in[9];
    const float* gatAd = (const float*)d_in[10];
    const float* gatB  = (const float*)d_in[11];
    const float* bnG   = (const float*)d_in[12];
    const float* bnB   = (const float*)d_in[13];
    const float* bnM   = (const float*)d_in[14];
    const float* bnV   = (const float*)d_in[15];
    const float* seW1  = (const float*)d_in[16];
    const float* seb1  = (const float*)d_in[17];
    const float* seW2  = (const float*)d_in[18];
    const float* seb2  = (const float*)d_in[19];
    const float* oW1   = (const float*)d_in[20];
    const float* ob1   = (const float*)d_in[21];
    const float* oW2   = (const float*)d_in[22];
    const float* ob2   = (const float*)d_in[23];
    const float* oW3   = (const float*)d_in[24];
    const float* ob3   = (const float*)d_in[25];
    float* out = (float*)d_out;

    const int N    = in_sizes[0] / 128;
    const int E    = in_sizes[1] / 2;
    const int Etot = E + N;

    float* ws      = (float*)d_ws;
    float* hbuf    = ws;
    float* zbuf    = hbuf + (size_t)N * 64;
    float* es      = zbuf + (size_t)N * 64;
    float* ed      = es + N;
    // ---- zero region (one memset) ----
    float* deg     = ed + N;
    float* inflsum = deg + N;
    unsigned* scal = (unsigned*)(inflsum + N);     // 8 slots
    int* cnt       = (int*)(scal + 8);
    int* cursor    = cnt + N;
    int* gcur      = cursor + N;                   // 8 slots
    // ---- end zero region ----
    int* startp    = gcur + 8;
    float* inflv   = (float*)(startp + N);
    int* esrc      = (int*)(inflv + N);            // Etot ints

    dim3 blk(256);
    int wv4     = (N + NP - 1) / NP;                      // waves in 4-node kernels
    int blkWv4  = (wv4 * 64 + 255) / 256;
    int blkE    = (E + 255) / 256;
    int blkEtot = (Etot + 255) / 256;
    int blkN    = (N + 255) / 256;
    int blkNW   = (N * 64 + 255) / 256;                   // wave per node

    hipMemsetAsync(deg, 0, ((size_t)4 * N + 16) * sizeof(float), stream);

    k_mlp<<<blkWv4, blk, 0, stream>>>(x, faW1, fab1, faW2, fab2, projW, projb, hbuf, N);

    // structural + CSR build (independent of k_mlp)
    k_deg<<<blkE, blk, 0, stream>>>(ei, E, deg);
    k_inflsum<<<blkE, blk, 0, stream>>>(ei, E, deg, inflsum);
    k_infl<<<blkN, blk, 0, stream>>>(deg, inflsum, inflv, scal, N);
    k_hist<<<blkEtot, blk, 0, stream>>>(ei, E, Etot, cnt);
    k_alloc<<<blkN, blk, 0, stream>>>(cnt, startp, gcur, N);
    k_fill<<<blkEtot, blk, 0, stream>>>(ei, E, Etot, startp, cursor, esrc);

    for (int l = 0; l < 3; ++l) {
        k_z<<<blkWv4, blk, 0, stream>>>(hbuf, gatW + l * 4096, gatAs + l * 64, gatAd + l * 64,
                                        zbuf, es, ed, N);
        k_agg<<<blkNW, blk, 0, stream>>>(startp, cnt, esrc, es, ed, zbuf,
                                         gatB + l * 64, bnG + l * 64, bnB + l * 64,
                                         bnM + l * 64, bnV + l * 64, hbuf, N);
    }

    k_final<<<blkWv4, blk, 0, stream>>>(hbuf, deg, inflv, scal, seW1, seb1, seW2, seb2,
                                        oW1, ob1, oW2, ob2, oW3, ob3, out, N);
}

// Round 3
// 5576.782 us; speedup vs baseline: 1.0048x; 1.0048x over previous
//
#include <hip/hip_runtime.h>

#define NP 4  // nodes per wave in the dense per-node kernels

// ---------------- node MLP: feature attention + projection ----------------
// fw = sigmoid(relu(x@faW1+b1)@faW2+b2); h = (x*fw)@projW + projb
// 4 nodes per wave: each weight load feeds 8 FMAs, 4 independent chains.
// __launch_bounds__(256,3): 168 VGPR budget — without it the compiler caps at
// 64 VGPRs and spills ~370 KB/wave to scratch (round-2: 9.3 GB HBM traffic).
__global__ void __launch_bounds__(256, 3)
k_mlp(const float* __restrict__ x,
      const float* __restrict__ faW1, const float* __restrict__ fab1,
      const float* __restrict__ faW2, const float* __restrict__ fab2,
      const float* __restrict__ projW, const float* __restrict__ projb,
      float* __restrict__ hbuf, int N) {
    int w    = (blockIdx.x * blockDim.x + threadIdx.x) >> 6;
    int lane = threadIdx.x & 63;
    int n0 = w * NP;
    if (n0 >= N) return;

    float x0[NP], x1[NP];
#pragma unroll
    for (int k = 0; k < NP; ++k) {
        int n = n0 + k < N ? n0 + k : N - 1;
        x0[k] = x[(size_t)n * 128 + lane];
        x1[k] = x[(size_t)n * 128 + 64 + lane];
    }

    // t = relu(x @ faW1 + b1)   [64]
    float t[NP];
#pragma unroll
    for (int k = 0; k < NP; ++k) t[k] = fab1[lane];
#pragma unroll
    for (int i = 0; i < 64; ++i) {
        float w0 = faW1[i * 64 + lane];
        float w1 = faW1[(64 + i) * 64 + lane];
#pragma unroll
        for (int k = 0; k < NP; ++k) {
            t[k] = fmaf(__shfl(x0[k], i, 64), w0, t[k]);
            t[k] = fmaf(__shfl(x1[k], i, 64), w1, t[k]);
        }
    }
#pragma unroll
    for (int k = 0; k < NP; ++k) t[k] = fmaxf(t[k], 0.f);

    // f = t @ faW2 + b2  [128]; lane holds j=lane and j=64+lane
    float f0[NP], f1[NP];
#pragma unroll
    for (int k = 0; k < NP; ++k) { f0[k] = fab2[lane]; f1[k] = fab2[64 + lane]; }
#pragma unroll
    for (int j = 0; j < 64; ++j) {
        float w0 = faW2[j * 128 + lane];
        float w1 = faW2[j * 128 + 64 + lane];
#pragma unroll
        for (int k = 0; k < NP; ++k) {
            float tj = __shfl(t[k], j, 64);
            f0[k] = fmaf(tj, w0, f0[k]);
            f1[k] = fmaf(tj, w1, f1[k]);
        }
    }
    // xm = x * sigmoid(f)
#pragma unroll
    for (int k = 0; k < NP; ++k) {
        f0[k] = x0[k] / (1.f + __expf(-f0[k]));
        f1[k] = x1[k] / (1.f + __expf(-f1[k]));
    }

    // h = xm @ projW + projb  [64]
    float h[NP];
#pragma unroll
    for (int k = 0; k < NP; ++k) h[k] = projb[lane];
#pragma unroll
    for (int i = 0; i < 64; ++i) {
        float w0 = projW[i * 64 + lane];
        float w1 = projW[(64 + i) * 64 + lane];
#pragma unroll
        for (int k = 0; k < NP; ++k) {
            h[k] = fmaf(__shfl(f0[k], i, 64), w0, h[k]);
            h[k] = fmaf(__shfl(f1[k], i, 64), w1, h[k]);
        }
    }
#pragma unroll
    for (int k = 0; k < NP; ++k)
        if (n0 + k < N) hbuf[(size_t)(n0 + k) * 64 + lane] = h[k];
}

// ---------------- GAT: z = h@W, es = z.asrc, ed = z.adst ----------------
__global__ void __launch_bounds__(256, 3)
k_z(const float* __restrict__ hbuf, const float* __restrict__ W,
    const float* __restrict__ asrc, const float* __restrict__ adst,
    float* __restrict__ zbuf, float* __restrict__ es, float* __restrict__ ed,
    int N) {
    int w    = (blockIdx.x * blockDim.x + threadIdx.x) >> 6;
    int lane = threadIdx.x & 63;
    int n0 = w * NP;
    if (n0 >= N) return;

    float h[NP];
#pragma unroll
    for (int k = 0; k < NP; ++k) {
        int n = n0 + k < N ? n0 + k : N - 1;
        h[k] = hbuf[(size_t)n * 64 + lane];
    }
    float z[NP];
#pragma unroll
    for (int k = 0; k < NP; ++k) z[k] = 0.f;
#pragma unroll
    for (int i = 0; i < 64; ++i) {
        float wv = W[i * 64 + lane];
#pragma unroll
        for (int k = 0; k < NP; ++k)
            z[k] = fmaf(__shfl(h[k], i, 64), wv, z[k]);
    }
    float as = asrc[lane], ad = adst[lane];
    float vs[NP], vd[NP];
#pragma unroll
    for (int k = 0; k < NP; ++k) { vs[k] = z[k] * as; vd[k] = z[k] * ad; }
#pragma unroll
    for (int off = 32; off; off >>= 1) {
#pragma unroll
        for (int k = 0; k < NP; ++k) {
            vs[k] += __shfl_xor(vs[k], off, 64);
            vd[k] += __shfl_xor(vd[k], off, 64);
        }
    }
#pragma unroll
    for (int k = 0; k < NP; ++k)
        if (n0 + k < N) zbuf[(size_t)(n0 + k) * 64 + lane] = z[k];
    if (lane == 0) {
#pragma unroll
        for (int k = 0; k < NP; ++k)
            if (n0 + k < N) { es[n0 + k] = vs[k]; ed[n0 + k] = vd[k]; }
    }
}

// ---------------- CSR build (dst-grouped, self-loops appended) ----------------
__global__ void k_hist(const int* __restrict__ ei, int E, int Etot, int* __restrict__ cnt) {
    int i = blockIdx.x * blockDim.x + threadIdx.x;
    if (i >= Etot) return;
    int d = i < E ? ei[E + i] : i - E;
    atomicAdd(&cnt[d], 1);
}

// per-wave exclusive scan + single bump-alloc atomic per wave
__global__ void k_alloc(const int* __restrict__ cnt, int* __restrict__ start,
                        int* __restrict__ gcur, int N) {
    int idx  = blockIdx.x * blockDim.x + threadIdx.x;
    int lane = threadIdx.x & 63;
    int c = idx < N ? cnt[idx] : 0;
    int sc = c;
#pragma unroll
    for (int off = 1; off < 64; off <<= 1) {
        int t = __shfl_up(sc, off, 64);
        if (lane >= off) sc += t;
    }
    int base = 0;
    if (lane == 63) base = atomicAdd(gcur, sc);
    base = __shfl(base, 63, 64);
    if (idx < N) start[idx] = base + sc - c;
}

__global__ void k_fill(const int* __restrict__ ei, int E, int Etot,
                       const int* __restrict__ start, int* __restrict__ cursor,
                       int* __restrict__ esrc) {
    int i = blockIdx.x * blockDim.x + threadIdx.x;
    if (i >= Etot) return;
    int s, d;
    if (i < E) { s = ei[i]; d = ei[E + i]; } else { s = d = i - E; }
    int p = atomicAdd(&cursor[d], 1);
    esrc[start[d] + p] = s;
}

// ---------------- fused GAT aggregation: softmax + scatter + bias + BN + ReLU ----
// one wave per dst node; lane = feature. No float atomics anywhere.
__global__ void k_agg(const int* __restrict__ start, const int* __restrict__ cnt,
                      const int* __restrict__ esrc,
                      const float* __restrict__ es, const float* __restrict__ ed,
                      const float* __restrict__ zbuf,
                      const float* __restrict__ b, const float* __restrict__ g,
                      const float* __restrict__ bta, const float* __restrict__ mean,
                      const float* __restrict__ var,
                      float* __restrict__ hbuf, int N) {
    int wid  = (blockIdx.x * blockDim.x + threadIdx.x) >> 6;
    int lane = threadIdx.x & 63;
    if (wid >= N) return;
    int row0 = start[wid];
    int c    = cnt[wid];          // >= 1 (self-loop)
    float edn = ed[wid];

    // phase A: segment max (lanes parallel over edges)
    float m = -1e30f;
    for (int k = lane; k < c; k += 64) {
        float e = es[esrc[row0 + k]] + edn;
        e = e >= 0.f ? e : 0.2f * e;
        m = fmaxf(m, e);
    }
#pragma unroll
    for (int off = 32; off; off >>= 1) m = fmaxf(m, __shfl_xor(m, off, 64));

    // phase B: denom
    float ssum = 0.f;
    for (int k = lane; k < c; k += 64) {
        float e = es[esrc[row0 + k]] + edn;
        e = e >= 0.f ? e : 0.2f * e;
        ssum += __expf(e - m);
    }
#pragma unroll
    for (int off = 32; off; off >>= 1) ssum += __shfl_xor(ssum, off, 64);

    // phase C: acc = sum z[src]*exp(e-m), software-pipelined gather
    float acc = 0.f;
    int   s  = esrc[row0];
    float zv = zbuf[(size_t)s * 64 + lane];
    float ep = es[s] + edn; ep = ep >= 0.f ? ep : 0.2f * ep;
    for (int k = 1; k < c; ++k) {
        int   s1 = esrc[row0 + k];
        float zn = zbuf[(size_t)s1 * 64 + lane];
        float en = es[s1] + edn; en = en >= 0.f ? en : 0.2f * en;
        acc = fmaf(zv, __expf(ep - m), acc);
        zv = zn; ep = en;
    }
    acc = fmaf(zv, __expf(ep - m), acc);
    acc /= ssum;

    // epilogue: +bias, BN(eval), ReLU
    float sc = g[lane] * rsqrtf(var[lane] + 1e-5f);
    float v  = (acc + b[lane] - mean[lane]) * sc + bta[lane];
    hbuf[(size_t)wid * 64 + lane] = fmaxf(v, 0.f);
}

// ---------------- structural ----------------
__global__ void k_deg(const int* __restrict__ ei, int E, float* __restrict__ deg) {
    int e = blockIdx.x * blockDim.x + threadIdx.x;
    if (e < E) atomicAdd(&deg[ei[e]], 1.f);
}
__global__ void k_inflsum(const int* __restrict__ ei, int E,
                          const float* __restrict__ deg, float* __restrict__ inflsum) {
    int e = blockIdx.x * blockDim.x + threadIdx.x;
    if (e < E) atomicAdd(&inflsum[ei[e]], deg[ei[E + e]]);
}
__global__ void k_infl(const float* __restrict__ deg, const float* __restrict__ inflsum,
                       float* __restrict__ inflv, unsigned* __restrict__ scal, int N) {
    int idx = blockIdx.x * blockDim.x + threadIdx.x;
    float d = 0.f, iv = 0.f;
    if (idx < N) {
        d = deg[idx];
        iv = d > 0.f ? inflsum[idx] / d : 0.f;
        inflv[idx] = iv;
    }
    float dm = d, im = iv;
#pragma unroll
    for (int off = 32; off; off >>= 1) {
        dm = fmaxf(dm, __shfl_xor(dm, off, 64));
        im = fmaxf(im, __shfl_xor(im, off, 64));
    }
    if ((threadIdx.x & 63) == 0) {
        atomicMax(scal + 0, __float_as_uint(dm));   // non-negative: bits order-preserving
        atomicMax(scal + 1, __float_as_uint(im));
    }
}

// ---------------- structural MLP + concat + output MLP (4 nodes/wave) --------
__global__ void __launch_bounds__(256, 3)
k_final(const float* __restrict__ hbuf, const float* __restrict__ deg,
        const float* __restrict__ inflv, const unsigned* __restrict__ scal,
        const float* __restrict__ seW1, const float* __restrict__ seb1,
        const float* __restrict__ seW2, const float* __restrict__ seb2,
        const float* __restrict__ oW1, const float* __restrict__ ob1,
        const float* __restrict__ oW2, const float* __restrict__ ob2,
        const float* __restrict__ oW3, const float* __restrict__ ob3,
        float* __restrict__ out, int N) {
    int w    = (blockIdx.x * blockDim.x + threadIdx.x) >> 6;
    int lane = threadIdx.x & 63;
    int n0 = w * NP;
    if (n0 >= N) return;
    int lk = lane & 31;

    float degmax  = fmaxf(__uint_as_float(scal[0]), 1.0f);
    float inflmax = fmaxf(__uint_as_float(scal[1]), 1e-12f);

    float h[NP], hid[NP];
#pragma unroll
    for (int k = 0; k < NP; ++k) {
        int n = n0 + k < N ? n0 + k : N - 1;
        h[k] = hbuf[(size_t)n * 64 + lane];
        float nd = deg[n] / degmax;
        float fl = inflv[n] / inflmax;
        hid[k] = fmaxf(nd * seW1[lk] + fl * seW1[64 + lk] + seb1[lk], 0.f);
    }

    // se = hidden @ seW2 + seb2   [64]
    float se[NP];
#pragma unroll
    for (int k = 0; k < NP; ++k) se[k] = seb2[lane];
#pragma unroll
    for (int j = 0; j < 32; ++j) {
        float wv = seW2[j * 64 + lane];
#pragma unroll
        for (int k = 0; k < NP; ++k)
            se[k] = fmaf(__shfl(hid[k], j, 64), wv, se[k]);
    }

    // o1 = relu([h, se] @ oW1 + ob1)  [64]
    float o1[NP];
#pragma unroll
    for (int k = 0; k < NP; ++k) o1[k] = ob1[lane];
#pragma unroll
    for (int i = 0; i < 64; ++i) {
        float w0 = oW1[i * 64 + lane];
        float w1 = oW1[(64 + i) * 64 + lane];
#pragma unroll
        for (int k = 0; k < NP; ++k) {
            o1[k] = fmaf(__shfl(h[k], i, 64),  w0, o1[k]);
            o1[k] = fmaf(__shfl(se[k], i, 64), w1, o1[k]);
        }
    }
#pragma unroll
    for (int k = 0; k < NP; ++k) o1[k] = fmaxf(o1[k], 0.f);

    // o2 = relu(o1 @ oW2 + ob2)  [32] (upper 32 lanes duplicate)
    float o2[NP];
#pragma unroll
    for (int k = 0; k < NP; ++k) o2[k] = ob2[lk];
#pragma unroll
    for (int j = 0; j < 64; ++j) {
        float wv = oW2[j * 32 + lk];
#pragma unroll
        for (int k = 0; k < NP; ++k)
            o2[k] = fmaf(__shfl(o1[k], j, 64), wv, o2[k]);
    }

    // out = sigmoid(o2 @ oW3 + ob3)
    float cacc[NP];
#pragma unroll
    for (int k = 0; k < NP; ++k) {
        o2[k] = fmaxf(o2[k], 0.f);
        cacc[k] = (lane < 32) ? o2[k] * oW3[lk] : 0.f;
    }
#pragma unroll
    for (int off = 32; off; off >>= 1)
#pragma unroll
        for (int k = 0; k < NP; ++k) cacc[k] += __shfl_xor(cacc[k], off, 64);
    if (lane == 0) {
#pragma unroll
        for (int k = 0; k < NP; ++k)
            if (n0 + k < N) out[n0 + k] = 1.f / (1.f + __expf(-(cacc[k] + ob3[0])));
    }
}

// ---------------- launch ----------------
extern "C" void kernel_launch(void* const* d_in, const int* in_sizes, int n_in,
                              void* d_out, int out_size, void* d_ws, size_t ws_size,
                              hipStream_t stream) {
    const float* x     = (const float*)d_in[0];
    const int*   ei    = (const int*)d_in[1];
    const float* faW1  = (const float*)d_in[2];
    const float* fab1  = (const float*)d_in[3];
    const float* faW2  = (const float*)d_in[4];
    const float* fab2  = (const float*)d_in[5];
    const float* projW = (const float*)d_in[6];
    const float* projb = (const float*)d_in[7];
    const float* gatW  = (const float*)d_in[8];
    const float* gatAs = (const float*)d_in[9];
    const float* gatAd = (const float*)d_in[10];
    const float* gatB  = (const float*)d_in[11];
    const float* bnG   = (const float*)d_in[12];
    const float* bnB   = (const float*)d_in[13];
    const float* bnM   = (const float*)d_in[14];
    const float* bnV   = (const float*)d_in[15];
    const float* seW1  = (const float*)d_in[16];
    const float* seb1  = (const float*)d_in[17];
    const float* seW2  = (const float*)d_in[18];
    const float* seb2  = (const float*)d_in[19];
    const float* oW1   = (const float*)d_in[20];
    const float* ob1   = (const float*)d_in[21];
    const float* oW2   = (const float*)d_in[22];
    const float* ob2   = (const float*)d_in[23];
    const float* oW3   = (const float*)d_in[24];
    const float* ob3   = (const float*)d_in[25];
    float* out = (float*)d_out;

    const int N    = in_sizes[0] / 128;
    const int E    = in_sizes[1] / 2;
    const int Etot = E + N;

    float* ws      = (float*)d_ws;
    float* hbuf    = ws;
    float* zbuf    = hbuf + (size_t)N * 64;
    float* es      = zbuf + (size_t)N * 64;
    float* ed      = es + N;
    // ---- zero region (one memset) ----
    float* deg     = ed + N;
    float* inflsum = deg + N;
    unsigned* scal = (unsigned*)(inflsum + N);     // 8 slots
    int* cnt       = (int*)(scal + 8);
    int* cursor    = cnt + N;
    int* gcur      = cursor + N;                   // 8 slots
    // ---- end zero region ----
    int* startp    = gcur + 8;
    float* inflv   = (float*)(startp + N);
    int* esrc      = (int*)(inflv + N);            // Etot ints

    dim3 blk(256);
    int wv4     = (N + NP - 1) / NP;                      // waves in 4-node kernels
    int blkWv4  = (wv4 * 64 + 255) / 256;
    int blkE    = (E + 255) / 256;
    int blkEtot = (Etot + 255) / 256;
    int blkN    = (N + 255) / 256;
    int blkNW   = (N * 64 + 255) / 256;                   // wave per node

    hipMemsetAsync(deg, 0, ((size_t)4 * N + 16) * sizeof(float), stream);

    k_mlp<<<blkWv4, blk, 0, stream>>>(x, faW1, fab1, faW2, fab2, projW, projb, hbuf, N);

    // structural + CSR build (independent of k_mlp)
    k_deg<<<blkE, blk, 0, stream>>>(ei, E, deg);
    k_inflsum<<<blkE, blk, 0, stream>>>(ei, E, deg, inflsum);
    k_infl<<<blkN, blk, 0, stream>>>(deg, inflsum, inflv, scal, N);
    k_hist<<<blkEtot, blk, 0, stream>>>(ei, E, Etot, cnt);
    k_alloc<<<blkN, blk, 0, stream>>>(cnt, startp, gcur, N);
    k_fill<<<blkEtot, blk, 0, stream>>>(ei, E, Etot, startp, cursor, esrc);

    for (int l = 0; l < 3; ++l) {
        k_z<<<blkWv4, blk, 0, stream>>>(hbuf, gatW + l * 4096, gatAs + l * 64, gatAd + l * 64,
                                        zbuf, es, ed, N);
        k_agg<<<blkNW, blk, 0, stream>>>(startp, cnt, esrc, es, ed, zbuf,
                                         gatB + l * 64, bnG + l * 64, bnB + l * 64,
                                         bnM + l * 64, bnV + l * 64, hbuf, N);
    }

    k_final<<<blkWv4, blk, 0, stream>>>(hbuf, deg, inflv, scal, seW1, seb1, seW2, seb2,
                                        oW1, ob1, oW2, ob2, oW3, ob3, out, N);
}

// Round 4
// 5109.300 us; speedup vs baseline: 1.0967x; 1.0915x over previous
//
#include <hip/hip_runtime.h>

#define NP 4  // nodes per wave in the dense per-node kernels
#define U4(S) S(0) S(1) S(2) S(3)

// ---------------- node MLP: feature attention + projection ----------------
// fw = sigmoid(relu(x@faW1+b1)@faW2+b2); h = (x*fw)@projW + projb
// 4 nodes per wave as NAMED SCALARS (no local arrays!). Round-2/3 lesson:
// float x0[4] indexed inside unrolled loops was lowered to scratch memory
// (5 KB/thread of private-segment traffic, 8.2 GB HBM/dispatch). Macro
// expansion guarantees registers.
__global__ void __launch_bounds__(256, 4)
k_mlp(const float* __restrict__ x,
      const float* __restrict__ faW1, const float* __restrict__ fab1,
      const float* __restrict__ faW2, const float* __restrict__ fab2,
      const float* __restrict__ projW, const float* __restrict__ projb,
      float* __restrict__ hbuf, int N) {
    int w    = (blockIdx.x * blockDim.x + threadIdx.x) >> 6;
    int lane = threadIdx.x & 63;
    int n0 = w * NP;
    if (n0 >= N) return;

#define DECLX(k) \
    int n_##k = (n0 + k < N) ? (n0 + k) : (N - 1); \
    float x0_##k = x[(size_t)n_##k * 128 + lane]; \
    float x1_##k = x[(size_t)n_##k * 128 + 64 + lane];
    U4(DECLX)
#undef DECLX

    // t = relu(x @ faW1 + b1)   [64]
#define DECLT(k) float t_##k = fab1[lane];
    U4(DECLT)
#undef DECLT
#pragma unroll
    for (int i = 0; i < 64; ++i) {
        float w0 = faW1[i * 64 + lane];
        float w1 = faW1[(64 + i) * 64 + lane];
#define S1(k) \
        t_##k = fmaf(__shfl(x0_##k, i, 64), w0, t_##k); \
        t_##k = fmaf(__shfl(x1_##k, i, 64), w1, t_##k);
        U4(S1)
#undef S1
    }
#define RELT(k) t_##k = fmaxf(t_##k, 0.f);
    U4(RELT)
#undef RELT

    // f = t @ faW2 + b2  [128]; lane holds j=lane and j=64+lane
#define DECLF(k) float f0_##k = fab2[lane]; float f1_##k = fab2[64 + lane];
    U4(DECLF)
#undef DECLF
#pragma unroll
    for (int j = 0; j < 64; ++j) {
        float w0 = faW2[j * 128 + lane];
        float w1 = faW2[j * 128 + 64 + lane];
#define S2(k) { \
        float tj = __shfl(t_##k, j, 64); \
        f0_##k = fmaf(tj, w0, f0_##k); \
        f1_##k = fmaf(tj, w1, f1_##k); }
        U4(S2)
#undef S2
    }
    // xm = x * sigmoid(f)
#define SIG(k) \
    f0_##k = x0_##k / (1.f + __expf(-f0_##k)); \
    f1_##k = x1_##k / (1.f + __expf(-f1_##k));
    U4(SIG)
#undef SIG

    // h = xm @ projW + projb  [64]
#define DECLH(k) float h_##k = projb[lane];
    U4(DECLH)
#undef DECLH
#pragma unroll
    for (int i = 0; i < 64; ++i) {
        float w0 = projW[i * 64 + lane];
        float w1 = projW[(64 + i) * 64 + lane];
#define S3(k) \
        h_##k = fmaf(__shfl(f0_##k, i, 64), w0, h_##k); \
        h_##k = fmaf(__shfl(f1_##k, i, 64), w1, h_##k);
        U4(S3)
#undef S3
    }
#define STH(k) if (n0 + k < N) hbuf[(size_t)(n0 + k) * 64 + lane] = h_##k;
    U4(STH)
#undef STH
}

// ---------------- GAT: z = h@W, es = z.asrc, ed = z.adst ----------------
__global__ void __launch_bounds__(256, 4)
k_z(const float* __restrict__ hbuf, const float* __restrict__ W,
    const float* __restrict__ asrc, const float* __restrict__ adst,
    float* __restrict__ zbuf, float* __restrict__ es, float* __restrict__ ed,
    int N) {
    int w    = (blockIdx.x * blockDim.x + threadIdx.x) >> 6;
    int lane = threadIdx.x & 63;
    int n0 = w * NP;
    if (n0 >= N) return;

#define DECLHZ(k) \
    int n_##k = (n0 + k < N) ? (n0 + k) : (N - 1); \
    float h_##k = hbuf[(size_t)n_##k * 64 + lane]; \
    float z_##k = 0.f;
    U4(DECLHZ)
#undef DECLHZ
#pragma unroll
    for (int i = 0; i < 64; ++i) {
        float wv = W[i * 64 + lane];
#define SZ(k) z_##k = fmaf(__shfl(h_##k, i, 64), wv, z_##k);
        U4(SZ)
#undef SZ
    }
    float as = asrc[lane], ad = adst[lane];
#define DECLV(k) float vs_##k = z_##k * as; float vd_##k = z_##k * ad;
    U4(DECLV)
#undef DECLV
#pragma unroll
    for (int off = 32; off; off >>= 1) {
#define RED(k) \
        vs_##k += __shfl_xor(vs_##k, off, 64); \
        vd_##k += __shfl_xor(vd_##k, off, 64);
        U4(RED)
#undef RED
    }
#define STZ(k) if (n0 + k < N) zbuf[(size_t)(n0 + k) * 64 + lane] = z_##k;
    U4(STZ)
#undef STZ
    if (lane == 0) {
#define STE(k) if (n0 + k < N) { es[n0 + k] = vs_##k; ed[n0 + k] = vd_##k; }
        U4(STE)
#undef STE
    }
}

// ---------------- CSR build (dst-grouped, self-loops appended) ----------------
__global__ void k_hist(const int* __restrict__ ei, int E, int Etot, int* __restrict__ cnt) {
    int i = blockIdx.x * blockDim.x + threadIdx.x;
    if (i >= Etot) return;
    int d = i < E ? ei[E + i] : i - E;
    atomicAdd(&cnt[d], 1);
}

// per-wave exclusive scan + single bump-alloc atomic per wave
__global__ void k_alloc(const int* __restrict__ cnt, int* __restrict__ start,
                        int* __restrict__ gcur, int N) {
    int idx  = blockIdx.x * blockDim.x + threadIdx.x;
    int lane = threadIdx.x & 63;
    int c = idx < N ? cnt[idx] : 0;
    int sc = c;
#pragma unroll
    for (int off = 1; off < 64; off <<= 1) {
        int t = __shfl_up(sc, off, 64);
        if (lane >= off) sc += t;
    }
    int base = 0;
    if (lane == 63) base = atomicAdd(gcur, sc);
    base = __shfl(base, 63, 64);
    if (idx < N) start[idx] = base + sc - c;
}

__global__ void k_fill(const int* __restrict__ ei, int E, int Etot,
                       const int* __restrict__ start, int* __restrict__ cursor,
                       int* __restrict__ esrc) {
    int i = blockIdx.x * blockDim.x + threadIdx.x;
    if (i >= Etot) return;
    int s, d;
    if (i < E) { s = ei[i]; d = ei[E + i]; } else { s = d = i - E; }
    int p = atomicAdd(&cursor[d], 1);
    esrc[start[d] + p] = s;
}

// ---------------- fused GAT aggregation: softmax + scatter + bias + BN + ReLU ----
// one wave per dst node; lane = feature. No float atomics anywhere.
__global__ void k_agg(const int* __restrict__ start, const int* __restrict__ cnt,
                      const int* __restrict__ esrc,
                      const float* __restrict__ es, const float* __restrict__ ed,
                      const float* __restrict__ zbuf,
                      const float* __restrict__ b, const float* __restrict__ g,
                      const float* __restrict__ bta, const float* __restrict__ mean,
                      const float* __restrict__ var,
                      float* __restrict__ hbuf, int N) {
    int wid  = (blockIdx.x * blockDim.x + threadIdx.x) >> 6;
    int lane = threadIdx.x & 63;
    if (wid >= N) return;
    int row0 = start[wid];
    int c    = cnt[wid];          // >= 1 (self-loop)
    float edn = ed[wid];

    // phase A: segment max (lanes parallel over edges)
    float m = -1e30f;
    for (int k = lane; k < c; k += 64) {
        float e = es[esrc[row0 + k]] + edn;
        e = e >= 0.f ? e : 0.2f * e;
        m = fmaxf(m, e);
    }
#pragma unroll
    for (int off = 32; off; off >>= 1) m = fmaxf(m, __shfl_xor(m, off, 64));

    // phase B: denom
    float ssum = 0.f;
    for (int k = lane; k < c; k += 64) {
        float e = es[esrc[row0 + k]] + edn;
        e = e >= 0.f ? e : 0.2f * e;
        ssum += __expf(e - m);
    }
#pragma unroll
    for (int off = 32; off; off >>= 1) ssum += __shfl_xor(ssum, off, 64);

    // phase C: acc = sum z[src]*exp(e-m), software-pipelined gather
    float acc = 0.f;
    int   s  = esrc[row0];
    float zv = zbuf[(size_t)s * 64 + lane];
    float ep = es[s] + edn; ep = ep >= 0.f ? ep : 0.2f * ep;
    for (int k = 1; k < c; ++k) {
        int   s1 = esrc[row0 + k];
        float zn = zbuf[(size_t)s1 * 64 + lane];
        float en = es[s1] + edn; en = en >= 0.f ? en : 0.2f * en;
        acc = fmaf(zv, __expf(ep - m), acc);
        zv = zn; ep = en;
    }
    acc = fmaf(zv, __expf(ep - m), acc);
    acc /= ssum;

    // epilogue: +bias, BN(eval), ReLU
    float sc = g[lane] * rsqrtf(var[lane] + 1e-5f);
    float v  = (acc + b[lane] - mean[lane]) * sc + bta[lane];
    hbuf[(size_t)wid * 64 + lane] = fmaxf(v, 0.f);
}

// ---------------- structural ----------------
__global__ void k_deg(const int* __restrict__ ei, int E, float* __restrict__ deg) {
    int e = blockIdx.x * blockDim.x + threadIdx.x;
    if (e < E) atomicAdd(&deg[ei[e]], 1.f);
}
__global__ void k_inflsum(const int* __restrict__ ei, int E,
                          const float* __restrict__ deg, float* __restrict__ inflsum) {
    int e = blockIdx.x * blockDim.x + threadIdx.x;
    if (e < E) atomicAdd(&inflsum[ei[e]], deg[ei[E + e]]);
}
__global__ void k_infl(const float* __restrict__ deg, const float* __restrict__ inflsum,
                       float* __restrict__ inflv, unsigned* __restrict__ scal, int N) {
    int idx = blockIdx.x * blockDim.x + threadIdx.x;
    float d = 0.f, iv = 0.f;
    if (idx < N) {
        d = deg[idx];
        iv = d > 0.f ? inflsum[idx] / d : 0.f;
        inflv[idx] = iv;
    }
    float dm = d, im = iv;
#pragma unroll
    for (int off = 32; off; off >>= 1) {
        dm = fmaxf(dm, __shfl_xor(dm, off, 64));
        im = fmaxf(im, __shfl_xor(im, off, 64));
    }
    if ((threadIdx.x & 63) == 0) {
        atomicMax(scal + 0, __float_as_uint(dm));   // non-negative: bits order-preserving
        atomicMax(scal + 1, __float_as_uint(im));
    }
}

// ---------------- structural MLP + concat + output MLP (4 nodes/wave) --------
__global__ void __launch_bounds__(256, 4)
k_final(const float* __restrict__ hbuf, const float* __restrict__ deg,
        const float* __restrict__ inflv, const unsigned* __restrict__ scal,
        const float* __restrict__ seW1, const float* __restrict__ seb1,
        const float* __restrict__ seW2, const float* __restrict__ seb2,
        const float* __restrict__ oW1, const float* __restrict__ ob1,
        const float* __restrict__ oW2, const float* __restrict__ ob2,
        const float* __restrict__ oW3, const float* __restrict__ ob3,
        float* __restrict__ out, int N) {
    int w    = (blockIdx.x * blockDim.x + threadIdx.x) >> 6;
    int lane = threadIdx.x & 63;
    int n0 = w * NP;
    if (n0 >= N) return;
    int lk = lane & 31;

    float degmax  = fmaxf(__uint_as_float(scal[0]), 1.0f);
    float inflmax = fmaxf(__uint_as_float(scal[1]), 1e-12f);
    float sw0 = seW1[lk], sw1 = seW1[64 + lk], sb1v = seb1[lk];

#define DECLHF(k) \
    int n_##k = (n0 + k < N) ? (n0 + k) : (N - 1); \
    float h_##k = hbuf[(size_t)n_##k * 64 + lane]; \
    float hid_##k = fmaxf((deg[n_##k] / degmax) * sw0 + (inflv[n_##k] / inflmax) * sw1 + sb1v, 0.f);
    U4(DECLHF)
#undef DECLHF

    // se = hidden @ seW2 + seb2   [64]
#define DECLSE(k) float se_##k = seb2[lane];
    U4(DECLSE)
#undef DECLSE
#pragma unroll
    for (int j = 0; j < 32; ++j) {
        float wv = seW2[j * 64 + lane];
#define SSE(k) se_##k = fmaf(__shfl(hid_##k, j, 64), wv, se_##k);
        U4(SSE)
#undef SSE
    }

    // o1 = relu([h, se] @ oW1 + ob1)  [64]
#define DECLO1(k) float o1_##k = ob1[lane];
    U4(DECLO1)
#undef DECLO1
#pragma unroll
    for (int i = 0; i < 64; ++i) {
        float w0 = oW1[i * 64 + lane];
        float w1 = oW1[(64 + i) * 64 + lane];
#define SO1(k) \
        o1_##k = fmaf(__shfl(h_##k, i, 64),  w0, o1_##k); \
        o1_##k = fmaf(__shfl(se_##k, i, 64), w1, o1_##k);
        U4(SO1)
#undef SO1
    }
#define RELO1(k) o1_##k = fmaxf(o1_##k, 0.f);
    U4(RELO1)
#undef RELO1

    // o2 = relu(o1 @ oW2 + ob2)  [32] (upper 32 lanes duplicate)
#define DECLO2(k) float o2_##k = ob2[lk];
    U4(DECLO2)
#undef DECLO2
#pragma unroll
    for (int j = 0; j < 64; ++j) {
        float wv = oW2[j * 32 + lk];
#define SO2(k) o2_##k = fmaf(__shfl(o1_##k, j, 64), wv, o2_##k);
        U4(SO2)
#undef SO2
    }

    // out = sigmoid(o2 @ oW3 + ob3)
    float w3 = oW3[lk];
#define DECLC(k) o2_##k = fmaxf(o2_##k, 0.f); \
    float c_##k = (lane < 32) ? o2_##k * w3 : 0.f;
    U4(DECLC)
#undef DECLC
#pragma unroll
    for (int off = 32; off; off >>= 1) {
#define REDC(k) c_##k += __shfl_xor(c_##k, off, 64);
        U4(REDC)
#undef REDC
    }
    if (lane == 0) {
#define STO(k) if (n0 + k < N) out[n0 + k] = 1.f / (1.f + __expf(-(c_##k + ob3[0])));
        U4(STO)
#undef STO
    }
}

// ---------------- launch ----------------
extern "C" void kernel_launch(void* const* d_in, const int* in_sizes, int n_in,
                              void* d_out, int out_size, void* d_ws, size_t ws_size,
                              hipStream_t stream) {
    const float* x     = (const float*)d_in[0];
    const int*   ei    = (const int*)d_in[1];
    const float* faW1  = (const float*)d_in[2];
    const float* fab1  = (const float*)d_in[3];
    const float* faW2  = (const float*)d_in[4];
    const float* fab2  = (const float*)d_in[5];
    const float* projW = (const float*)d_in[6];
    const float* projb = (const float*)d_in[7];
    const float* gatW  = (const float*)d_in[8];
    const float* gatAs = (const float*)d_in[9];
    const float* gatAd = (const float*)d_in[10];
    const float* gatB  = (const float*)d_in[11];
    const float* bnG   = (const float*)d_in[12];
    const float* bnB   = (const float*)d_in[13];
    const float* bnM   = (const float*)d_in[14];
    const float* bnV   = (const float*)d_in[15];
    const float* seW1  = (const float*)d_in[16];
    const float* seb1  = (const float*)d_in[17];
    const float* seW2  = (const float*)d_in[18];
    const float* seb2  = (const float*)d_in[19];
    const float* oW1   = (const float*)d_in[20];
    const float* ob1   = (const float*)d_in[21];
    const float* oW2   = (const float*)d_in[22];
    const float* ob2   = (const float*)d_in[23];
    const float* oW3   = (const float*)d_in[24];
    const float* ob3   = (const float*)d_in[25];
    float* out = (float*)d_out;

    const int N    = in_sizes[0] / 128;
    const int E    = in_sizes[1] / 2;
    const int Etot = E + N;

    float* ws      = (float*)d_ws;
    float* hbuf    = ws;
    float* zbuf    = hbuf + (size_t)N * 64;
    float* es      = zbuf + (size_t)N * 64;
    float* ed      = es + N;
    // ---- zero region (one memset) ----
    float* deg     = ed + N;
    float* inflsum = deg + N;
    unsigned* scal = (unsigned*)(inflsum + N);     // 8 slots
    int* cnt       = (int*)(scal + 8);
    int* cursor    = cnt + N;
    int* gcur      = cursor + N;                   // 8 slots
    // ---- end zero region ----
    int* startp    = gcur + 8;
    float* inflv   = (float*)(startp + N);
    int* esrc      = (int*)(inflv + N);            // Etot ints

    dim3 blk(256);
    int wv4     = (N + NP - 1) / NP;                      // waves in 4-node kernels
    int blkWv4  = (wv4 * 64 + 255) / 256;
    int blkE    = (E + 255) / 256;
    int blkEtot = (Etot + 255) / 256;
    int blkN    = (N + 255) / 256;
    int blkNW   = (N * 64 + 255) / 256;                   // wave per node

    hipMemsetAsync(deg, 0, ((size_t)4 * N + 16) * sizeof(float), stream);

    k_mlp<<<blkWv4, blk, 0, stream>>>(x, faW1, fab1, faW2, fab2, projW, projb, hbuf, N);

    // structural + CSR build (independent of k_mlp)
    k_deg<<<blkE, blk, 0, stream>>>(ei, E, deg);
    k_inflsum<<<blkE, blk, 0, stream>>>(ei, E, deg, inflsum);
    k_infl<<<blkN, blk, 0, stream>>>(deg, inflsum, inflv, scal, N);
    k_hist<<<blkEtot, blk, 0, stream>>>(ei, E, Etot, cnt);
    k_alloc<<<blkN, blk, 0, stream>>>(cnt, startp, gcur, N);
    k_fill<<<blkEtot, blk, 0, stream>>>(ei, E, Etot, startp, cursor, esrc);

    for (int l = 0; l < 3; ++l) {
        k_z<<<blkWv4, blk, 0, stream>>>(hbuf, gatW + l * 4096, gatAs + l * 64, gatAd + l * 64,
                                        zbuf, es, ed, N);
        k_agg<<<blkNW, blk, 0, stream>>>(startp, cnt, esrc, es, ed, zbuf,
                                         gatB + l * 64, bnG + l * 64, bnB + l * 64,
                                         bnM + l * 64, bnV + l * 64, hbuf, N);
    }

    k_final<<<blkWv4, blk, 0, stream>>>(hbuf, deg, inflv, scal, seW1, seb1, seW2, seb2,
                                        oW1, ob1, oW2, ob2, oW3, ob3, out, N);
}

// Round 5
// 1741.340 us; speedup vs baseline: 3.2179x; 2.9341x over previous
//
#include <hip/hip_runtime.h>

#define NP 4  // nodes per wave in the dense per-node kernels
#define U4(S) S(0) S(1) S(2) S(3)

// Round-4 post-mortem: full unroll of the 64-iter GEMV loops made the
// scheduler hoist ~128 weight loads; allocator stayed at 64 VGPR (targeting
// 8 waves/EU) and spilled ~5.5 GB/dispatch to scratch.
// Fix: #pragma unroll 8 (bounded hoist window) + amdgpu_waves_per_eu(4,4)
// (pin occupancy target so the full 128-VGPR budget is actually used).

// ---------------- node MLP: feature attention + projection ----------------
// fw = sigmoid(relu(x@faW1+b1)@faW2+b2); h = (x*fw)@projW + projb
__global__ __attribute__((amdgpu_waves_per_eu(4, 4))) void __launch_bounds__(256)
k_mlp(const float* __restrict__ x,
      const float* __restrict__ faW1, const float* __restrict__ fab1,
      const float* __restrict__ faW2, const float* __restrict__ fab2,
      const float* __restrict__ projW, const float* __restrict__ projb,
      float* __restrict__ hbuf, int N) {
    int w    = (blockIdx.x * blockDim.x + threadIdx.x) >> 6;
    int lane = threadIdx.x & 63;
    int n0 = w * NP;
    if (n0 >= N) return;

#define DECLX(k) \
    int n_##k = (n0 + k < N) ? (n0 + k) : (N - 1); \
    float x0_##k = x[(size_t)n_##k * 128 + lane]; \
    float x1_##k = x[(size_t)n_##k * 128 + 64 + lane];
    U4(DECLX)
#undef DECLX

    // t = relu(x @ faW1 + b1)   [64]
#define DECLT(k) float t_##k = fab1[lane];
    U4(DECLT)
#undef DECLT
#pragma unroll 8
    for (int i = 0; i < 64; ++i) {
        float w0 = faW1[i * 64 + lane];
        float w1 = faW1[(64 + i) * 64 + lane];
#define S1(k) \
        t_##k = fmaf(__shfl(x0_##k, i, 64), w0, t_##k); \
        t_##k = fmaf(__shfl(x1_##k, i, 64), w1, t_##k);
        U4(S1)
#undef S1
    }
#define RELT(k) t_##k = fmaxf(t_##k, 0.f);
    U4(RELT)
#undef RELT

    // f = t @ faW2 + b2  [128]; lane holds j=lane and j=64+lane
#define DECLF(k) float f0_##k = fab2[lane]; float f1_##k = fab2[64 + lane];
    U4(DECLF)
#undef DECLF
#pragma unroll 8
    for (int j = 0; j < 64; ++j) {
        float w0 = faW2[j * 128 + lane];
        float w1 = faW2[j * 128 + 64 + lane];
#define S2(k) { \
        float tj = __shfl(t_##k, j, 64); \
        f0_##k = fmaf(tj, w0, f0_##k); \
        f1_##k = fmaf(tj, w1, f1_##k); }
        U4(S2)
#undef S2
    }
    // xm = x * sigmoid(f)
#define SIG(k) \
    f0_##k = x0_##k / (1.f + __expf(-f0_##k)); \
    f1_##k = x1_##k / (1.f + __expf(-f1_##k));
    U4(SIG)
#undef SIG

    // h = xm @ projW + projb  [64]
#define DECLH(k) float h_##k = projb[lane];
    U4(DECLH)
#undef DECLH
#pragma unroll 8
    for (int i = 0; i < 64; ++i) {
        float w0 = projW[i * 64 + lane];
        float w1 = projW[(64 + i) * 64 + lane];
#define S3(k) \
        h_##k = fmaf(__shfl(f0_##k, i, 64), w0, h_##k); \
        h_##k = fmaf(__shfl(f1_##k, i, 64), w1, h_##k);
        U4(S3)
#undef S3
    }
#define STH(k) if (n0 + k < N) hbuf[(size_t)(n0 + k) * 64 + lane] = h_##k;
    U4(STH)
#undef STH
}

// ---------------- GAT: z = h@W, es = z.asrc, ed = z.adst ----------------
__global__ __attribute__((amdgpu_waves_per_eu(4, 4))) void __launch_bounds__(256)
k_z(const float* __restrict__ hbuf, const float* __restrict__ W,
    const float* __restrict__ asrc, const float* __restrict__ adst,
    float* __restrict__ zbuf, float* __restrict__ es, float* __restrict__ ed,
    int N) {
    int w    = (blockIdx.x * blockDim.x + threadIdx.x) >> 6;
    int lane = threadIdx.x & 63;
    int n0 = w * NP;
    if (n0 >= N) return;

#define DECLHZ(k) \
    int n_##k = (n0 + k < N) ? (n0 + k) : (N - 1); \
    float h_##k = hbuf[(size_t)n_##k * 64 + lane]; \
    float z_##k = 0.f;
    U4(DECLHZ)
#undef DECLHZ
#pragma unroll 8
    for (int i = 0; i < 64; ++i) {
        float wv = W[i * 64 + lane];
#define SZ(k) z_##k = fmaf(__shfl(h_##k, i, 64), wv, z_##k);
        U4(SZ)
#undef SZ
    }
    float as = asrc[lane], ad = adst[lane];
#define DECLV(k) float vs_##k = z_##k * as; float vd_##k = z_##k * ad;
    U4(DECLV)
#undef DECLV
#pragma unroll
    for (int off = 32; off; off >>= 1) {
#define RED(k) \
        vs_##k += __shfl_xor(vs_##k, off, 64); \
        vd_##k += __shfl_xor(vd_##k, off, 64);
        U4(RED)
#undef RED
    }
#define STZ(k) if (n0 + k < N) zbuf[(size_t)(n0 + k) * 64 + lane] = z_##k;
    U4(STZ)
#undef STZ
    if (lane == 0) {
#define STE(k) if (n0 + k < N) { es[n0 + k] = vs_##k; ed[n0 + k] = vd_##k; }
        U4(STE)
#undef STE
    }
}

// ---------------- CSR build (dst-grouped, self-loops appended) ----------------
__global__ void k_hist(const int* __restrict__ ei, int E, int Etot, int* __restrict__ cnt) {
    int i = blockIdx.x * blockDim.x + threadIdx.x;
    if (i >= Etot) return;
    int d = i < E ? ei[E + i] : i - E;
    atomicAdd(&cnt[d], 1);
}

// per-wave exclusive scan + single bump-alloc atomic per wave
__global__ void k_alloc(const int* __restrict__ cnt, int* __restrict__ start,
                        int* __restrict__ gcur, int N) {
    int idx  = blockIdx.x * blockDim.x + threadIdx.x;
    int lane = threadIdx.x & 63;
    int c = idx < N ? cnt[idx] : 0;
    int sc = c;
#pragma unroll
    for (int off = 1; off < 64; off <<= 1) {
        int t = __shfl_up(sc, off, 64);
        if (lane >= off) sc += t;
    }
    int base = 0;
    if (lane == 63) base = atomicAdd(gcur, sc);
    base = __shfl(base, 63, 64);
    if (idx < N) start[idx] = base + sc - c;
}

__global__ void k_fill(const int* __restrict__ ei, int E, int Etot,
                       const int* __restrict__ start, int* __restrict__ cursor,
                       int* __restrict__ esrc) {
    int i = blockIdx.x * blockDim.x + threadIdx.x;
    if (i >= Etot) return;
    int s, d;
    if (i < E) { s = ei[i]; d = ei[E + i]; } else { s = d = i - E; }
    int p = atomicAdd(&cursor[d], 1);
    esrc[start[d] + p] = s;
}

// ---------------- fused GAT aggregation: softmax + scatter + bias + BN + ReLU ----
// one wave per dst node; lane = feature. No float atomics anywhere.
__global__ void k_agg(const int* __restrict__ start, const int* __restrict__ cnt,
                      const int* __restrict__ esrc,
                      const float* __restrict__ es, const float* __restrict__ ed,
                      const float* __restrict__ zbuf,
                      const float* __restrict__ b, const float* __restrict__ g,
                      const float* __restrict__ bta, const float* __restrict__ mean,
                      const float* __restrict__ var,
                      float* __restrict__ hbuf, int N) {
    int wid  = (blockIdx.x * blockDim.x + threadIdx.x) >> 6;
    int lane = threadIdx.x & 63;
    if (wid >= N) return;
    int row0 = start[wid];
    int c    = cnt[wid];          // >= 1 (self-loop)
    float edn = ed[wid];

    // phase A: segment max (lanes parallel over edges)
    float m = -1e30f;
    for (int k = lane; k < c; k += 64) {
        float e = es[esrc[row0 + k]] + edn;
        e = e >= 0.f ? e : 0.2f * e;
        m = fmaxf(m, e);
    }
#pragma unroll
    for (int off = 32; off; off >>= 1) m = fmaxf(m, __shfl_xor(m, off, 64));

    // phase B: denom
    float ssum = 0.f;
    for (int k = lane; k < c; k += 64) {
        float e = es[esrc[row0 + k]] + edn;
        e = e >= 0.f ? e : 0.2f * e;
        ssum += __expf(e - m);
    }
#pragma unroll
    for (int off = 32; off; off >>= 1) ssum += __shfl_xor(ssum, off, 64);

    // phase C: acc = sum z[src]*exp(e-m), software-pipelined gather
    float acc = 0.f;
    int   s  = esrc[row0];
    float zv = zbuf[(size_t)s * 64 + lane];
    float ep = es[s] + edn; ep = ep >= 0.f ? ep : 0.2f * ep;
    for (int k = 1; k < c; ++k) {
        int   s1 = esrc[row0 + k];
        float zn = zbuf[(size_t)s1 * 64 + lane];
        float en = es[s1] + edn; en = en >= 0.f ? en : 0.2f * en;
        acc = fmaf(zv, __expf(ep - m), acc);
        zv = zn; ep = en;
    }
    acc = fmaf(zv, __expf(ep - m), acc);
    acc /= ssum;

    // epilogue: +bias, BN(eval), ReLU
    float sc = g[lane] * rsqrtf(var[lane] + 1e-5f);
    float v  = (acc + b[lane] - mean[lane]) * sc + bta[lane];
    hbuf[(size_t)wid * 64 + lane] = fmaxf(v, 0.f);
}

// ---------------- structural ----------------
__global__ void k_deg(const int* __restrict__ ei, int E, float* __restrict__ deg) {
    int e = blockIdx.x * blockDim.x + threadIdx.x;
    if (e < E) atomicAdd(&deg[ei[e]], 1.f);
}
__global__ void k_inflsum(const int* __restrict__ ei, int E,
                          const float* __restrict__ deg, float* __restrict__ inflsum) {
    int e = blockIdx.x * blockDim.x + threadIdx.x;
    if (e < E) atomicAdd(&inflsum[ei[e]], deg[ei[E + e]]);
}
__global__ void k_infl(const float* __restrict__ deg, const float* __restrict__ inflsum,
                       float* __restrict__ inflv, unsigned* __restrict__ scal, int N) {
    int idx = blockIdx.x * blockDim.x + threadIdx.x;
    float d = 0.f, iv = 0.f;
    if (idx < N) {
        d = deg[idx];
        iv = d > 0.f ? inflsum[idx] / d : 0.f;
        inflv[idx] = iv;
    }
    float dm = d, im = iv;
#pragma unroll
    for (int off = 32; off; off >>= 1) {
        dm = fmaxf(dm, __shfl_xor(dm, off, 64));
        im = fmaxf(im, __shfl_xor(im, off, 64));
    }
    if ((threadIdx.x & 63) == 0) {
        atomicMax(scal + 0, __float_as_uint(dm));   // non-negative: bits order-preserving
        atomicMax(scal + 1, __float_as_uint(im));
    }
}

// ---------------- structural MLP + concat + output MLP (4 nodes/wave) --------
__global__ __attribute__((amdgpu_waves_per_eu(4, 4))) void __launch_bounds__(256)
k_final(const float* __restrict__ hbuf, const float* __restrict__ deg,
        const float* __restrict__ inflv, const unsigned* __restrict__ scal,
        const float* __restrict__ seW1, const float* __restrict__ seb1,
        const float* __restrict__ seW2, const float* __restrict__ seb2,
        const float* __restrict__ oW1, const float* __restrict__ ob1,
        const float* __restrict__ oW2, const float* __restrict__ ob2,
        const float* __restrict__ oW3, const float* __restrict__ ob3,
        float* __restrict__ out, int N) {
    int w    = (blockIdx.x * blockDim.x + threadIdx.x) >> 6;
    int lane = threadIdx.x & 63;
    int n0 = w * NP;
    if (n0 >= N) return;
    int lk = lane & 31;

    float degmax  = fmaxf(__uint_as_float(scal[0]), 1.0f);
    float inflmax = fmaxf(__uint_as_float(scal[1]), 1e-12f);
    float sw0 = seW1[lk], sw1 = seW1[64 + lk], sb1v = seb1[lk];

#define DECLHF(k) \
    int n_##k = (n0 + k < N) ? (n0 + k) : (N - 1); \
    float h_##k = hbuf[(size_t)n_##k * 64 + lane]; \
    float hid_##k = fmaxf((deg[n_##k] / degmax) * sw0 + (inflv[n_##k] / inflmax) * sw1 + sb1v, 0.f);
    U4(DECLHF)
#undef DECLHF

    // se = hidden @ seW2 + seb2   [64]
#define DECLSE(k) float se_##k = seb2[lane];
    U4(DECLSE)
#undef DECLSE
#pragma unroll 8
    for (int j = 0; j < 32; ++j) {
        float wv = seW2[j * 64 + lane];
#define SSE(k) se_##k = fmaf(__shfl(hid_##k, j, 64), wv, se_##k);
        U4(SSE)
#undef SSE
    }

    // o1 = relu([h, se] @ oW1 + ob1)  [64]
#define DECLO1(k) float o1_##k = ob1[lane];
    U4(DECLO1)
#undef DECLO1
#pragma unroll 8
    for (int i = 0; i < 64; ++i) {
        float w0 = oW1[i * 64 + lane];
        float w1 = oW1[(64 + i) * 64 + lane];
#define SO1(k) \
        o1_##k = fmaf(__shfl(h_##k, i, 64),  w0, o1_##k); \
        o1_##k = fmaf(__shfl(se_##k, i, 64), w1, o1_##k);
        U4(SO1)
#undef SO1
    }
#define RELO1(k) o1_##k = fmaxf(o1_##k, 0.f);
    U4(RELO1)
#undef RELO1

    // o2 = relu(o1 @ oW2 + ob2)  [32] (upper 32 lanes duplicate)
#define DECLO2(k) float o2_##k = ob2[lk];
    U4(DECLO2)
#undef DECLO2
#pragma unroll 8
    for (int j = 0; j < 64; ++j) {
        float wv = oW2[j * 32 + lk];
#define SO2(k) o2_##k = fmaf(__shfl(o1_##k, j, 64), wv, o2_##k);
        U4(SO2)
#undef SO2
    }

    // out = sigmoid(o2 @ oW3 + ob3)
    float w3 = oW3[lk];
#define DECLC(k) o2_##k = fmaxf(o2_##k, 0.f); \
    float c_##k = (lane < 32) ? o2_##k * w3 : 0.f;
    U4(DECLC)
#undef DECLC
#pragma unroll
    for (int off = 32; off; off >>= 1) {
#define REDC(k) c_##k += __shfl_xor(c_##k, off, 64);
        U4(REDC)
#undef REDC
    }
    if (lane == 0) {
#define STO(k) if (n0 + k < N) out[n0 + k] = 1.f / (1.f + __expf(-(c_##k + ob3[0])));
        U4(STO)
#undef STO
    }
}

// ---------------- launch ----------------
extern "C" void kernel_launch(void* const* d_in, const int* in_sizes, int n_in,
                              void* d_out, int out_size, void* d_ws, size_t ws_size,
                              hipStream_t stream) {
    const float* x     = (const float*)d_in[0];
    const int*   ei    = (const int*)d_in[1];
    const float* faW1  = (const float*)d_in[2];
    const float* fab1  = (const float*)d_in[3];
    const float* faW2  = (const float*)d_in[4];
    const float* fab2  = (const float*)d_in[5];
    const float* projW = (const float*)d_in[6];
    const float* projb = (const float*)d_in[7];
    const float* gatW  = (const float*)d_in[8];
    const float* gatAs = (const float*)d_in[9];
    const float* gatAd = (const float*)d_in[10];
    const float* gatB  = (const float*)d_in[11];
    const float* bnG   = (const float*)d_in[12];
    const float* bnB   = (const float*)d_in[13];
    const float* bnM   = (const float*)d_in[14];
    const float* bnV   = (const float*)d_in[15];
    const float* seW1  = (const float*)d_in[16];
    const float* seb1  = (const float*)d_in[17];
    const float* seW2  = (const float*)d_in[18];
    const float* seb2  = (const float*)d_in[19];
    const float* oW1   = (const float*)d_in[20];
    const float* ob1   = (const float*)d_in[21];
    const float* oW2   = (const float*)d_in[22];
    const float* ob2   = (const float*)d_in[23];
    const float* oW3   = (const float*)d_in[24];
    const float* ob3   = (const float*)d_in[25];
    float* out = (float*)d_out;

    const int N    = in_sizes[0] / 128;
    const int E    = in_sizes[1] / 2;
    const int Etot = E + N;

    float* ws      = (float*)d_ws;
    float* hbuf    = ws;
    float* zbuf    = hbuf + (size_t)N * 64;
    float* es      = zbuf + (size_t)N * 64;
    float* ed      = es + N;
    // ---- zero region (one memset) ----
    float* deg     = ed + N;
    float* inflsum = deg + N;
    unsigned* scal = (unsigned*)(inflsum + N);     // 8 slots
    int* cnt       = (int*)(scal + 8);
    int* cursor    = cnt + N;
    int* gcur      = cursor + N;                   // 8 slots
    // ---- end zero region ----
    int* startp    = gcur + 8;
    float* inflv   = (float*)(startp + N);
    int* esrc      = (int*)(inflv + N);            // Etot ints

    dim3 blk(256);
    int wv4     = (N + NP - 1) / NP;                      // waves in 4-node kernels
    int blkWv4  = (wv4 * 64 + 255) / 256;
    int blkE    = (E + 255) / 256;
    int blkEtot = (Etot + 255) / 256;
    int blkN    = (N + 255) / 256;
    int blkNW   = (N * 64 + 255) / 256;                   // wave per node

    hipMemsetAsync(deg, 0, ((size_t)4 * N + 16) * sizeof(float), stream);

    k_mlp<<<blkWv4, blk, 0, stream>>>(x, faW1, fab1, faW2, fab2, projW, projb, hbuf, N);

    // structural + CSR build (independent of k_mlp)
    k_deg<<<blkE, blk, 0, stream>>>(ei, E, deg);
    k_inflsum<<<blkE, blk, 0, stream>>>(ei, E, deg, inflsum);
    k_infl<<<blkN, blk, 0, stream>>>(deg, inflsum, inflv, scal, N);
    k_hist<<<blkEtot, blk, 0, stream>>>(ei, E, Etot, cnt);
    k_alloc<<<blkN, blk, 0, stream>>>(cnt, startp, gcur, N);
    k_fill<<<blkEtot, blk, 0, stream>>>(ei, E, Etot, startp, cursor, esrc);

    for (int l = 0; l < 3; ++l) {
        k_z<<<blkWv4, blk, 0, stream>>>(hbuf, gatW + l * 4096, gatAs + l * 64, gatAd + l * 64,
                                        zbuf, es, ed, N);
        k_agg<<<blkNW, blk, 0, stream>>>(startp, cnt, esrc, es, ed, zbuf,
                                         gatB + l * 64, bnG + l * 64, bnB + l * 64,
                                         bnM + l * 64, bnV + l * 64, hbuf, N);
    }

    k_final<<<blkWv4, blk, 0, stream>>>(hbuf, deg, inflv, scal, seW1, seb1, seW2, seb2,
                                        oW1, ob1, oW2, ob2, oW3, ob3, out, N);
}

// Round 6
// 1240.651 us; speedup vs baseline: 4.5165x; 1.4036x over previous
//
#include <hip/hip_runtime.h>

// r5 post-mortem: dense kernels were DS-pipe-bound (1280 ds_bpermute per
// 4-node wave from __shfl broadcasts; VALUBusy 16%). r6: lane-per-node
// structure — weights are wave-uniform (SGPR broadcast via scalar loads),
// intermediates in registers (const-indexed via full j-unroll), zero DS ops.
// Register discipline (r2-r5 lessons): pin waves_per_eu; keep outer c-loops
// at unroll 1; fully unroll every loop that indexes a register array.

// ---------------- prep: fold se branch into o1 weights ----------------
// M2[k][j] = sum_i seW2[k][i] * oW1[64+i][j];  b2f[j] = ob1[j] + sum_i seb2[i]*oW1[64+i][j]
__global__ void k_prep(const float* __restrict__ seW2, const float* __restrict__ seb2,
                       const float* __restrict__ oW1, const float* __restrict__ ob1,
                       float* __restrict__ M2, float* __restrict__ b2f) {
    int tid = threadIdx.x;  // one block of 256
    for (int o = tid; o < 32 * 64; o += 256) {
        int k = o >> 6, j = o & 63;
        float s = 0.f;
        for (int i = 0; i < 64; ++i)
            s = fmaf(seW2[k * 64 + i], oW1[(64 + i) * 64 + j], s);
        M2[o] = s;
    }
    for (int j = tid; j < 64; j += 256) {
        float s = ob1[j];
        for (int i = 0; i < 64; ++i)
            s = fmaf(seb2[i], oW1[(64 + i) * 64 + j], s);
        b2f[j] = s;
    }
}

// ---------------- node MLP: feature attention + projection ----------------
// lane = node. fw = sigmoid(relu(x@faW1+b1)@faW2+b2); h = (x*fw)@projW + projb
__global__ __attribute__((amdgpu_waves_per_eu(3, 3))) void __launch_bounds__(256)
k_mlp(const float* __restrict__ x,
      const float* __restrict__ faW1, const float* __restrict__ fab1,
      const float* __restrict__ faW2, const float* __restrict__ fab2,
      const float* __restrict__ projW, const float* __restrict__ projb,
      float* __restrict__ hbuf, int N) {
    int tid = blockIdx.x * blockDim.x + threadIdx.x;
    int n = tid < N ? tid : N - 1;
    const float* xr = x + (size_t)n * 128;

    // t = relu(x @ faW1 + b1)  [64] — all in VGPRs, weights via SGPR
    float t[64];
#pragma unroll
    for (int j = 0; j < 64; ++j) t[j] = fab1[j];
#pragma unroll 1
    for (int c = 0; c < 32; ++c) {
        float4 xv = *reinterpret_cast<const float4*>(xr + c * 4);
        const float* wb = faW1 + c * 4 * 64;
#pragma unroll
        for (int j = 0; j < 64; ++j) {
            t[j] = fmaf(xv.x, wb[j], t[j]);
            t[j] = fmaf(xv.y, wb[64 + j], t[j]);
            t[j] = fmaf(xv.z, wb[128 + j], t[j]);
            t[j] = fmaf(xv.w, wb[192 + j], t[j]);
        }
    }
#pragma unroll
    for (int j = 0; j < 64; ++j) t[j] = fmaxf(t[j], 0.f);

    // fused: f_i = t@faW2[:,i]+b2_i; xm_i = x_i*sigmoid(f_i); h += xm_i*projW[i,:]
    float h[64];
#pragma unroll
    for (int j = 0; j < 64; ++j) h[j] = projb[j];
#pragma unroll 1
    for (int c = 0; c < 32; ++c) {
        float4 xv = *reinterpret_cast<const float4*>(xr + c * 4);
        int i0 = c * 4;
        float f0 = fab2[i0], f1 = fab2[i0 + 1], f2 = fab2[i0 + 2], f3 = fab2[i0 + 3];
        const float* w2 = faW2 + i0;
#pragma unroll
        for (int j = 0; j < 64; ++j) {
            float tj = t[j];
            f0 = fmaf(tj, w2[j * 128], f0);
            f1 = fmaf(tj, w2[j * 128 + 1], f1);
            f2 = fmaf(tj, w2[j * 128 + 2], f2);
            f3 = fmaf(tj, w2[j * 128 + 3], f3);
        }
        float xm0 = xv.x / (1.f + __expf(-f0));
        float xm1 = xv.y / (1.f + __expf(-f1));
        float xm2 = xv.z / (1.f + __expf(-f2));
        float xm3 = xv.w / (1.f + __expf(-f3));
        const float* wp = projW + i0 * 64;
#pragma unroll
        for (int j = 0; j < 64; ++j) {
            h[j] = fmaf(xm0, wp[j], h[j]);
            h[j] = fmaf(xm1, wp[64 + j], h[j]);
            h[j] = fmaf(xm2, wp[128 + j], h[j]);
            h[j] = fmaf(xm3, wp[192 + j], h[j]);
        }
    }
    if (tid < N) {
        float* hr = hbuf + (size_t)tid * 64;
#pragma unroll
        for (int c = 0; c < 16; ++c) {
            float4 v = make_float4(h[c * 4], h[c * 4 + 1], h[c * 4 + 2], h[c * 4 + 3]);
            *reinterpret_cast<float4*>(hr + c * 4) = v;
        }
    }
}

// ---------------- GAT: z = h@W, es = z.asrc, ed = z.adst ----------------
__global__ __attribute__((amdgpu_waves_per_eu(4, 4))) void __launch_bounds__(256)
k_z(const float* __restrict__ hbuf, const float* __restrict__ W,
    const float* __restrict__ asrc, const float* __restrict__ adst,
    float* __restrict__ zbuf, float* __restrict__ es, float* __restrict__ ed, int N) {
    int tid = blockIdx.x * blockDim.x + threadIdx.x;
    int n = tid < N ? tid : N - 1;
    const float* hr = hbuf + (size_t)n * 64;
    float z[64];
#pragma unroll
    for (int j = 0; j < 64; ++j) z[j] = 0.f;
#pragma unroll 1
    for (int c = 0; c < 16; ++c) {
        float4 hv = *reinterpret_cast<const float4*>(hr + c * 4);
        const float* wb = W + c * 4 * 64;
#pragma unroll
        for (int j = 0; j < 64; ++j) {
            z[j] = fmaf(hv.x, wb[j], z[j]);
            z[j] = fmaf(hv.y, wb[64 + j], z[j]);
            z[j] = fmaf(hv.z, wb[128 + j], z[j]);
            z[j] = fmaf(hv.w, wb[192 + j], z[j]);
        }
    }
    float e0 = 0, e1 = 0, e2 = 0, e3 = 0, d0 = 0, d1 = 0, d2 = 0, d3 = 0;
#pragma unroll
    for (int j = 0; j < 64; j += 4) {
        e0 = fmaf(z[j], asrc[j], e0);
        e1 = fmaf(z[j + 1], asrc[j + 1], e1);
        e2 = fmaf(z[j + 2], asrc[j + 2], e2);
        e3 = fmaf(z[j + 3], asrc[j + 3], e3);
        d0 = fmaf(z[j], adst[j], d0);
        d1 = fmaf(z[j + 1], adst[j + 1], d1);
        d2 = fmaf(z[j + 2], adst[j + 2], d2);
        d3 = fmaf(z[j + 3], adst[j + 3], d3);
    }
    if (tid < N) {
        float* zr = zbuf + (size_t)tid * 64;
#pragma unroll
        for (int c = 0; c < 16; ++c) {
            float4 v = make_float4(z[c * 4], z[c * 4 + 1], z[c * 4 + 2], z[c * 4 + 3]);
            *reinterpret_cast<float4*>(zr + c * 4) = v;
        }
        es[tid] = (e0 + e1) + (e2 + e3);
        ed[tid] = (d0 + d1) + (d2 + d3);
    }
}

// ---------------- CSR build (dst-grouped, self-loops appended) ----------------
__global__ void k_hist(const int* __restrict__ ei, int E, int Etot, int* __restrict__ cnt) {
    int i = blockIdx.x * blockDim.x + threadIdx.x;
    if (i >= Etot) return;
    int d = i < E ? ei[E + i] : i - E;
    atomicAdd(&cnt[d], 1);
}

__global__ void k_alloc(const int* __restrict__ cnt, int* __restrict__ start,
                        int* __restrict__ gcur, int N) {
    int idx  = blockIdx.x * blockDim.x + threadIdx.x;
    int lane = threadIdx.x & 63;
    int c = idx < N ? cnt[idx] : 0;
    int sc = c;
#pragma unroll
    for (int off = 1; off < 64; off <<= 1) {
        int t = __shfl_up(sc, off, 64);
        if (lane >= off) sc += t;
    }
    int base = 0;
    if (lane == 63) base = atomicAdd(gcur, sc);
    base = __shfl(base, 63, 64);
    if (idx < N) start[idx] = base + sc - c;
}

__global__ void k_fill(const int* __restrict__ ei, int E, int Etot,
                       const int* __restrict__ start, int* __restrict__ cursor,
                       int* __restrict__ esrc) {
    int i = blockIdx.x * blockDim.x + threadIdx.x;
    if (i >= Etot) return;
    int s, d;
    if (i < E) { s = ei[i]; d = ei[E + i]; } else { s = d = i - E; }
    int p = atomicAdd(&cursor[d], 1);
    esrc[start[d] + p] = s;
}

// ---------------- fused GAT aggregation: softmax + scatter + bias + BN + ReLU ----
__global__ void k_agg(const int* __restrict__ start, const int* __restrict__ cnt,
                      const int* __restrict__ esrc,
                      const float* __restrict__ es, const float* __restrict__ ed,
                      const float* __restrict__ zbuf,
                      const float* __restrict__ b, const float* __restrict__ g,
                      const float* __restrict__ bta, const float* __restrict__ mean,
                      const float* __restrict__ var,
                      float* __restrict__ hbuf, int N) {
    int wid  = (blockIdx.x * blockDim.x + threadIdx.x) >> 6;
    int lane = threadIdx.x & 63;
    if (wid >= N) return;
    int row0 = start[wid];
    int c    = cnt[wid];          // >= 1 (self-loop)
    float edn = ed[wid];

    float m = -1e30f;
    for (int k = lane; k < c; k += 64) {
        float e = es[esrc[row0 + k]] + edn;
        e = e >= 0.f ? e : 0.2f * e;
        m = fmaxf(m, e);
    }
#pragma unroll
    for (int off = 32; off; off >>= 1) m = fmaxf(m, __shfl_xor(m, off, 64));

    float ssum = 0.f;
    for (int k = lane; k < c; k += 64) {
        float e = es[esrc[row0 + k]] + edn;
        e = e >= 0.f ? e : 0.2f * e;
        ssum += __expf(e - m);
    }
#pragma unroll
    for (int off = 32; off; off >>= 1) ssum += __shfl_xor(ssum, off, 64);

    float acc = 0.f;
    int   s  = esrc[row0];
    float zv = zbuf[(size_t)s * 64 + lane];
    float ep = es[s] + edn; ep = ep >= 0.f ? ep : 0.2f * ep;
    for (int k = 1; k < c; ++k) {
        int   s1 = esrc[row0 + k];
        float zn = zbuf[(size_t)s1 * 64 + lane];
        float en = es[s1] + edn; en = en >= 0.f ? en : 0.2f * en;
        acc = fmaf(zv, __expf(ep - m), acc);
        zv = zn; ep = en;
    }
    acc = fmaf(zv, __expf(ep - m), acc);
    acc /= ssum;

    float sc = g[lane] * rsqrtf(var[lane] + 1e-5f);
    float v  = (acc + b[lane] - mean[lane]) * sc + bta[lane];
    hbuf[(size_t)wid * 64 + lane] = fmaxf(v, 0.f);
}

// ---------------- structural ----------------
__global__ void k_deg(const int* __restrict__ ei, int E, float* __restrict__ deg) {
    int e = blockIdx.x * blockDim.x + threadIdx.x;
    if (e < E) atomicAdd(&deg[ei[e]], 1.f);
}
__global__ void k_inflsum(const int* __restrict__ ei, int E,
                          const float* __restrict__ deg, float* __restrict__ inflsum) {
    int e = blockIdx.x * blockDim.x + threadIdx.x;
    if (e < E) atomicAdd(&inflsum[ei[e]], deg[ei[E + e]]);
}
__global__ void k_infl(const float* __restrict__ deg, const float* __restrict__ inflsum,
                       float* __restrict__ inflv, unsigned* __restrict__ scal, int N) {
    int idx = blockIdx.x * blockDim.x + threadIdx.x;
    float d = 0.f, iv = 0.f;
    if (idx < N) {
        d = deg[idx];
        iv = d > 0.f ? inflsum[idx] / d : 0.f;
        inflv[idx] = iv;
    }
    float dm = d, im = iv;
#pragma unroll
    for (int off = 32; off; off >>= 1) {
        dm = fmaxf(dm, __shfl_xor(dm, off, 64));
        im = fmaxf(im, __shfl_xor(im, off, 64));
    }
    if ((threadIdx.x & 63) == 0) {
        atomicMax(scal + 0, __float_as_uint(dm));   // non-negative: bits order-preserving
        atomicMax(scal + 1, __float_as_uint(im));
    }
}

// ---------------- output head: lane = node ----------------
// o1 = relu(h@oW1_up + hid@M2 + b2f); o2 = relu(o1@oW2+ob2); out = sigmoid(o2@oW3+ob3)
__global__ __attribute__((amdgpu_waves_per_eu(4, 4))) void __launch_bounds__(256)
k_final(const float* __restrict__ hbuf, const float* __restrict__ deg,
        const float* __restrict__ inflv, const unsigned* __restrict__ scal,
        const float* __restrict__ seW1, const float* __restrict__ seb1,
        const float* __restrict__ M2, const float* __restrict__ b2f,
        const float* __restrict__ oW1,
        const float* __restrict__ oW2, const float* __restrict__ ob2,
        const float* __restrict__ oW3, const float* __restrict__ ob3,
        float* __restrict__ out, int N) {
    int tid = blockIdx.x * blockDim.x + threadIdx.x;
    int n = tid < N ? tid : N - 1;

    float degmax  = fmaxf(__uint_as_float(scal[0]), 1.0f);
    float inflmax = fmaxf(__uint_as_float(scal[1]), 1e-12f);
    float nd = deg[n] / degmax;
    float fl = inflv[n] / inflmax;

    // hid = relu(sf @ seW1 + seb1), sf = [nd, 0, fl]
    float hid[32];
#pragma unroll
    for (int k = 0; k < 32; ++k)
        hid[k] = fmaxf(fmaf(nd, seW1[k], fmaf(fl, seW1[64 + k], seb1[k])), 0.f);

    // o1 accumulate: folded-se part first (hid dies), then h part
    float o1[64];
#pragma unroll
    for (int j = 0; j < 64; ++j) o1[j] = b2f[j];
#pragma unroll
    for (int k = 0; k < 32; ++k) {
#pragma unroll
        for (int j = 0; j < 64; ++j)
            o1[j] = fmaf(hid[k], M2[k * 64 + j], o1[j]);
    }
    const float* hr = hbuf + (size_t)n * 64;
#pragma unroll 1
    for (int c = 0; c < 16; ++c) {
        float4 hv = *reinterpret_cast<const float4*>(hr + c * 4);
        const float* wb = oW1 + c * 4 * 64;
#pragma unroll
        for (int j = 0; j < 64; ++j) {
            o1[j] = fmaf(hv.x, wb[j], o1[j]);
            o1[j] = fmaf(hv.y, wb[64 + j], o1[j]);
            o1[j] = fmaf(hv.z, wb[128 + j], o1[j]);
            o1[j] = fmaf(hv.w, wb[192 + j], o1[j]);
        }
    }
#pragma unroll
    for (int j = 0; j < 64; ++j) o1[j] = fmaxf(o1[j], 0.f);

    float o2[32];
#pragma unroll
    for (int k = 0; k < 32; ++k) o2[k] = ob2[k];
#pragma unroll
    for (int j = 0; j < 64; ++j) {
#pragma unroll
        for (int k = 0; k < 32; ++k)
            o2[k] = fmaf(o1[j], oW2[j * 32 + k], o2[k]);
    }
    float a0 = 0, a1 = 0, a2 = 0, a3 = 0;
#pragma unroll
    for (int k = 0; k < 32; k += 4) {
        a0 = fmaf(fmaxf(o2[k], 0.f), oW3[k], a0);
        a1 = fmaf(fmaxf(o2[k + 1], 0.f), oW3[k + 1], a1);
        a2 = fmaf(fmaxf(o2[k + 2], 0.f), oW3[k + 2], a2);
        a3 = fmaf(fmaxf(o2[k + 3], 0.f), oW3[k + 3], a3);
    }
    if (tid < N)
        out[tid] = 1.f / (1.f + __expf(-((a0 + a1) + (a2 + a3) + ob3[0])));
}

// ---------------- launch ----------------
extern "C" void kernel_launch(void* const* d_in, const int* in_sizes, int n_in,
                              void* d_out, int out_size, void* d_ws, size_t ws_size,
                              hipStream_t stream) {
    const float* x     = (const float*)d_in[0];
    const int*   ei    = (const int*)d_in[1];
    const float* faW1  = (const float*)d_in[2];
    const float* fab1  = (const float*)d_in[3];
    const float* faW2  = (const float*)d_in[4];
    const float* fab2  = (const float*)d_in[5];
    const float* projW = (const float*)d_in[6];
    const float* projb = (const float*)d_in[7];
    const float* gatW  = (const float*)d_in[8];
    const float* gatAs = (const float*)d_in[9];
    const float* gatAd = (const float*)d_in[10];
    const float* gatB  = (const float*)d_in[11];
    const float* bnG   = (const float*)d_in[12];
    const float* bnB   = (const float*)d_in[13];
    const float* bnM   = (const float*)d_in[14];
    const float* bnV   = (const float*)d_in[15];
    const float* seW1  = (const float*)d_in[16];
    const float* seb1  = (const float*)d_in[17];
    const float* seW2  = (const float*)d_in[18];
    const float* seb2  = (const float*)d_in[19];
    const float* oW1   = (const float*)d_in[20];
    const float* ob1   = (const float*)d_in[21];
    const float* oW2   = (const float*)d_in[22];
    const float* ob2   = (const float*)d_in[23];
    const float* oW3   = (const float*)d_in[24];
    const float* ob3   = (const float*)d_in[25];
    float* out = (float*)d_out;

    const int N    = in_sizes[0] / 128;
    const int E    = in_sizes[1] / 2;
    const int Etot = E + N;

    float* ws      = (float*)d_ws;
    float* hbuf    = ws;
    float* zbuf    = hbuf + (size_t)N * 64;
    float* es      = zbuf + (size_t)N * 64;
    float* ed      = es + N;
    // ---- zero region (one memset) ----
    float* deg     = ed + N;
    float* inflsum = deg + N;
    unsigned* scal = (unsigned*)(inflsum + N);     // 8 slots
    int* cnt       = (int*)(scal + 8);
    int* cursor    = cnt + N;
    int* gcur      = cursor + N;                   // 8 slots
    // ---- end zero region ----
    int* startp    = gcur + 8;
    float* inflv   = (float*)(startp + N);
    int* esrc      = (int*)(inflv + N);            // Etot ints
    float* M2      = (float*)(esrc + Etot);        // 32*64
    float* b2f     = M2 + 32 * 64;                 // 64

    dim3 blk(256);
    int blkN    = (N + 255) / 256;                 // lane-per-node dense kernels
    int blkE    = (E + 255) / 256;
    int blkEtot = (Etot + 255) / 256;
    int blkNW   = (N * 64 + 255) / 256;            // wave-per-node (k_agg)

    hipMemsetAsync(deg, 0, ((size_t)4 * N + 16) * sizeof(float), stream);

    k_prep<<<1, blk, 0, stream>>>(seW2, seb2, oW1, ob1, M2, b2f);
    k_mlp<<<blkN, blk, 0, stream>>>(x, faW1, fab1, faW2, fab2, projW, projb, hbuf, N);

    // structural + CSR build
    k_deg<<<blkE, blk, 0, stream>>>(ei, E, deg);
    k_inflsum<<<blkE, blk, 0, stream>>>(ei, E, deg, inflsum);
    k_infl<<<blkN, blk, 0, stream>>>(deg, inflsum, inflv, scal, N);
    k_hist<<<blkEtot, blk, 0, stream>>>(ei, E, Etot, cnt);
    k_alloc<<<blkN, blk, 0, stream>>>(cnt, startp, gcur, N);
    k_fill<<<blkEtot, blk, 0, stream>>>(ei, E, Etot, startp, cursor, esrc);

    for (int l = 0; l < 3; ++l) {
        k_z<<<blkN, blk, 0, stream>>>(hbuf, gatW + l * 4096, gatAs + l * 64, gatAd + l * 64,
                                      zbuf, es, ed, N);
        k_agg<<<blkNW, blk, 0, stream>>>(startp, cnt, esrc, es, ed, zbuf,
                                         gatB + l * 64, bnG + l * 64, bnB + l * 64,
                                         bnM + l * 64, bnV + l * 64, hbuf, N);
    }

    k_final<<<blkN, blk, 0, stream>>>(hbuf, deg, inflv, scal, seW1, seb1, M2, b2f,
                                      oW1, oW2, ob2, oW3, ob3, out, N);
}

// Round 7
// 979.731 us; speedup vs baseline: 5.7194x; 1.2663x over previous
//
#include <hip/hip_runtime.h>

// r6 post-mortem: dense kernels are grid-starved (N/64 = 1564 waves = 1.5/EU)
// and serialized on s_load->FMA per c-iter (VALUBusy 29%). k_agg re-gathers
// es/esrc 3x per edge. r7: single-pass k_agg (register-cached exp, softmax
// shift-invariance), stage fusion to backfill the machine, unroll 2.

// ---------------- fused stage 1: node MLP  ||  deg/cnt histograms  ||  prep ----
__global__ __attribute__((amdgpu_waves_per_eu(3, 3))) void __launch_bounds__(256)
k_fused1(const float* __restrict__ x,
         const float* __restrict__ faW1, const float* __restrict__ fab1,
         const float* __restrict__ faW2, const float* __restrict__ fab2,
         const float* __restrict__ projW, const float* __restrict__ projb,
         float* __restrict__ hbuf, int N,
         const int* __restrict__ ei, int E,
         float* __restrict__ deg, int* __restrict__ cnt,
         const float* __restrict__ seW2, const float* __restrict__ seb2,
         const float* __restrict__ oW1, const float* __restrict__ ob1,
         float* __restrict__ M2, float* __restrict__ b2f,
         int gMlp, int gEdge) {
    int bid = blockIdx.x;
    if (bid < gMlp) {
        // ---- node MLP: lane = node ----
        int tid = bid * blockDim.x + threadIdx.x;
        int n = tid < N ? tid : N - 1;
        const float* xr = x + (size_t)n * 128;

        float t[64];
#pragma unroll
        for (int j = 0; j < 64; ++j) t[j] = fab1[j];
#pragma unroll 2
        for (int c = 0; c < 32; ++c) {
            float4 xv = *reinterpret_cast<const float4*>(xr + c * 4);
            const float* wb = faW1 + c * 4 * 64;
#pragma unroll
            for (int j = 0; j < 64; ++j) {
                t[j] = fmaf(xv.x, wb[j], t[j]);
                t[j] = fmaf(xv.y, wb[64 + j], t[j]);
                t[j] = fmaf(xv.z, wb[128 + j], t[j]);
                t[j] = fmaf(xv.w, wb[192 + j], t[j]);
            }
        }
#pragma unroll
        for (int j = 0; j < 64; ++j) t[j] = fmaxf(t[j], 0.f);

        float h[64];
#pragma unroll
        for (int j = 0; j < 64; ++j) h[j] = projb[j];
#pragma unroll 2
        for (int c = 0; c < 32; ++c) {
            float4 xv = *reinterpret_cast<const float4*>(xr + c * 4);
            int i0 = c * 4;
            float f0 = fab2[i0], f1 = fab2[i0 + 1], f2 = fab2[i0 + 2], f3 = fab2[i0 + 3];
            const float* w2 = faW2 + i0;
#pragma unroll
            for (int j = 0; j < 64; ++j) {
                float tj = t[j];
                f0 = fmaf(tj, w2[j * 128], f0);
                f1 = fmaf(tj, w2[j * 128 + 1], f1);
                f2 = fmaf(tj, w2[j * 128 + 2], f2);
                f3 = fmaf(tj, w2[j * 128 + 3], f3);
            }
            float xm0 = xv.x / (1.f + __expf(-f0));
            float xm1 = xv.y / (1.f + __expf(-f1));
            float xm2 = xv.z / (1.f + __expf(-f2));
            float xm3 = xv.w / (1.f + __expf(-f3));
            const float* wp = projW + i0 * 64;
#pragma unroll
            for (int j = 0; j < 64; ++j) {
                h[j] = fmaf(xm0, wp[j], h[j]);
                h[j] = fmaf(xm1, wp[64 + j], h[j]);
                h[j] = fmaf(xm2, wp[128 + j], h[j]);
                h[j] = fmaf(xm3, wp[192 + j], h[j]);
            }
        }
        if (tid < N) {
            float* hr = hbuf + (size_t)tid * 64;
#pragma unroll
            for (int c = 0; c < 16; ++c)
                *reinterpret_cast<float4*>(hr + c * 4) =
                    make_float4(h[c * 4], h[c * 4 + 1], h[c * 4 + 2], h[c * 4 + 3]);
        }
    } else if (bid < gMlp + gEdge) {
        // ---- per-edge: src-degree + dst-count histograms ----
        int e = (bid - gMlp) * blockDim.x + threadIdx.x;
        if (e < E) {
            atomicAdd(&deg[ei[e]], 1.f);
            atomicAdd(&cnt[ei[E + e]], 1);
        }
    } else {
        // ---- prep: fold se branch into o1 weights ----
        int tid = threadIdx.x;
        for (int o = tid; o < 32 * 64; o += 256) {
            int k = o >> 6, j = o & 63;
            float s = 0.f;
            for (int i = 0; i < 64; ++i)
                s = fmaf(seW2[k * 64 + i], oW1[(64 + i) * 64 + j], s);
            M2[o] = s;
        }
        for (int j = tid; j < 64; j += 256) {
            float s = ob1[j];
            for (int i = 0; i < 64; ++i)
                s = fmaf(seb2[i], oW1[(64 + i) * 64 + j], s);
            b2f[j] = s;
        }
    }
}

// ---------------- fused stage 2: inflsum || CSR alloc (+self-loop slot) ------
__global__ void k_fused2(const int* __restrict__ ei, int E,
                         const float* __restrict__ deg, float* __restrict__ inflsum,
                         const int* __restrict__ cnt, int* __restrict__ startp,
                         int* __restrict__ esrc, int* __restrict__ gcur,
                         int N, int gEdge) {
    int bid = blockIdx.x;
    if (bid < gEdge) {
        int e = bid * blockDim.x + threadIdx.x;
        if (e < E) atomicAdd(&inflsum[ei[e]], deg[ei[E + e]]);
    } else {
        int idx  = (bid - gEdge) * blockDim.x + threadIdx.x;
        int lane = threadIdx.x & 63;
        int c = idx < N ? cnt[idx] + 1 : 0;   // +1: self-loop slot
        int sc = c;
#pragma unroll
        for (int off = 1; off < 64; off <<= 1) {
            int t = __shfl_up(sc, off, 64);
            if (lane >= off) sc += t;
        }
        int base = 0;
        if (lane == 63) base = atomicAdd(gcur, sc);
        base = __shfl(base, 63, 64);
        if (idx < N) {
            int st = base + sc - c;
            startp[idx] = st;
            esrc[st] = idx;                    // self-loop at slot 0
        }
    }
}

// ---------------- fused stage 3: CSR fill || structural infl -----------------
__global__ void k_fused3(const int* __restrict__ ei, int E,
                         const int* __restrict__ startp, int* __restrict__ cursor,
                         int* __restrict__ esrc,
                         const float* __restrict__ deg, const float* __restrict__ inflsum,
                         float* __restrict__ inflv, unsigned* __restrict__ scal,
                         int N, int gEdge) {
    int bid = blockIdx.x;
    if (bid < gEdge) {
        int e = bid * blockDim.x + threadIdx.x;
        if (e < E) {
            int s = ei[e], d = ei[E + e];
            int p = atomicAdd(&cursor[d], 1);
            esrc[startp[d] + 1 + p] = s;       // slots 1.. after self-loop
        }
    } else {
        int idx = (bid - gEdge) * blockDim.x + threadIdx.x;
        float dv = 0.f, iv = 0.f;
        if (idx < N) {
            dv = deg[idx];
            iv = dv > 0.f ? inflsum[idx] / dv : 0.f;
            inflv[idx] = iv;
        }
        float dm = dv, im = iv;
#pragma unroll
        for (int off = 32; off; off >>= 1) {
            dm = fmaxf(dm, __shfl_xor(dm, off, 64));
            im = fmaxf(im, __shfl_xor(im, off, 64));
        }
        if ((threadIdx.x & 63) == 0) {
            atomicMax(scal + 0, __float_as_uint(dm));
            atomicMax(scal + 1, __float_as_uint(im));
        }
    }
}

// ---------------- GAT: z = h@W, es = z.asrc, ed = z.adst ----------------
__global__ __attribute__((amdgpu_waves_per_eu(4, 4))) void __launch_bounds__(256)
k_z(const float* __restrict__ hbuf, const float* __restrict__ W,
    const float* __restrict__ asrc, const float* __restrict__ adst,
    float* __restrict__ zbuf, float* __restrict__ es, float* __restrict__ ed, int N) {
    int tid = blockIdx.x * blockDim.x + threadIdx.x;
    int n = tid < N ? tid : N - 1;
    const float* hr = hbuf + (size_t)n * 64;
    float z[64];
#pragma unroll
    for (int j = 0; j < 64; ++j) z[j] = 0.f;
#pragma unroll 2
    for (int c = 0; c < 16; ++c) {
        float4 hv = *reinterpret_cast<const float4*>(hr + c * 4);
        const float* wb = W + c * 4 * 64;
#pragma unroll
        for (int j = 0; j < 64; ++j) {
            z[j] = fmaf(hv.x, wb[j], z[j]);
            z[j] = fmaf(hv.y, wb[64 + j], z[j]);
            z[j] = fmaf(hv.z, wb[128 + j], z[j]);
            z[j] = fmaf(hv.w, wb[192 + j], z[j]);
        }
    }
    float e0 = 0, e1 = 0, e2 = 0, e3 = 0, d0 = 0, d1 = 0, d2 = 0, d3 = 0;
#pragma unroll
    for (int j = 0; j < 64; j += 4) {
        e0 = fmaf(z[j], asrc[j], e0);
        e1 = fmaf(z[j + 1], asrc[j + 1], e1);
        e2 = fmaf(z[j + 2], asrc[j + 2], e2);
        e3 = fmaf(z[j + 3], asrc[j + 3], e3);
        d0 = fmaf(z[j], adst[j], d0);
        d1 = fmaf(z[j + 1], adst[j + 1], d1);
        d2 = fmaf(z[j + 2], adst[j + 2], d2);
        d3 = fmaf(z[j + 3], adst[j + 3], d3);
    }
    if (tid < N) {
        float* zr = zbuf + (size_t)tid * 64;
#pragma unroll
        for (int c = 0; c < 16; ++c)
            *reinterpret_cast<float4*>(zr + c * 4) =
                make_float4(z[c * 4], z[c * 4 + 1], z[c * 4 + 2], z[c * 4 + 3]);
        es[tid] = (e0 + e1) + (e2 + e3);
        ed[tid] = (d0 + d1) + (d2 + d3);
    }
}

// ---------------- fused GAT aggregation: single-pass softmax + scatter + BN ----
// One wave per dst node; lane = feature. Softmax shift-invariance: skip the
// segment-max pass (|e| is O(1); exp safe in fp32). esrc + exp(e) cached in
// one register per lane (c<=64 common case); readlane-broadcast in the
// pipelined z-gather.
__global__ void k_agg(const int* __restrict__ start, const int* __restrict__ cnt,
                      const int* __restrict__ esrc,
                      const float* __restrict__ es, const float* __restrict__ ed,
                      const float* __restrict__ zbuf,
                      const float* __restrict__ b, const float* __restrict__ g,
                      const float* __restrict__ bta, const float* __restrict__ mean,
                      const float* __restrict__ var,
                      float* __restrict__ hbuf, int N) {
    int wid  = (blockIdx.x * blockDim.x + threadIdx.x) >> 6;
    int lane = threadIdx.x & 63;
    if (wid >= N) return;
    int row0 = start[wid];
    int c    = cnt[wid] + 1;       // +1 self-loop
    float edn = ed[wid];

    int   sreg = 0;
    float exv  = 0.f;
    if (lane < c) {
        sreg = esrc[row0 + lane];
        float e = es[sreg] + edn;
        e = e >= 0.f ? e : 0.2f * e;
        exv = __expf(e);
    }
    float ssum = exv;
    for (int k = 64 + lane; k < c; k += 64) {          // rare tail c>64
        int s = esrc[row0 + k];
        float e = es[s] + edn; e = e >= 0.f ? e : 0.2f * e;
        ssum += __expf(e);
    }
#pragma unroll
    for (int off = 32; off; off >>= 1) ssum += __shfl_xor(ssum, off, 64);

    float acc = 0.f;
    int kmax = c < 64 ? c : 64;
    int   sk = __shfl(sreg, 0, 64);
    float w  = __shfl(exv, 0, 64);
    float zv = zbuf[(size_t)sk * 64 + lane];
    for (int k = 1; k < kmax; ++k) {
        int   sk1 = __shfl(sreg, k, 64);
        float w1  = __shfl(exv, k, 64);
        float zn  = zbuf[(size_t)sk1 * 64 + lane];
        acc = fmaf(zv, w, acc);
        zv = zn; w = w1;
    }
    acc = fmaf(zv, w, acc);
    for (int k = 64; k < c; ++k) {                     // rare tail c>64
        int s = esrc[row0 + k];
        float e = es[s] + edn; e = e >= 0.f ? e : 0.2f * e;
        acc = fmaf(zbuf[(size_t)s * 64 + lane], __expf(e), acc);
    }
    acc /= ssum;

    float sc = g[lane] * rsqrtf(var[lane] + 1e-5f);
    float v  = (acc + b[lane] - mean[lane]) * sc + bta[lane];
    hbuf[(size_t)wid * 64 + lane] = fmaxf(v, 0.f);
}

// ---------------- output head: lane = node ----------------
__global__ __attribute__((amdgpu_waves_per_eu(4, 4))) void __launch_bounds__(256)
k_final(const float* __restrict__ hbuf, const float* __restrict__ deg,
        const float* __restrict__ inflv, const unsigned* __restrict__ scal,
        const float* __restrict__ seW1, const float* __restrict__ seb1,
        const float* __restrict__ M2, const float* __restrict__ b2f,
        const float* __restrict__ oW1,
        const float* __restrict__ oW2, const float* __restrict__ ob2,
        const float* __restrict__ oW3, const float* __restrict__ ob3,
        float* __restrict__ out, int N) {
    int tid = blockIdx.x * blockDim.x + threadIdx.x;
    int n = tid < N ? tid : N - 1;

    float degmax  = fmaxf(__uint_as_float(scal[0]), 1.0f);
    float inflmax = fmaxf(__uint_as_float(scal[1]), 1e-12f);
    float nd = deg[n] / degmax;
    float fl = inflv[n] / inflmax;

    float hid[32];
#pragma unroll
    for (int k = 0; k < 32; ++k)
        hid[k] = fmaxf(fmaf(nd, seW1[k], fmaf(fl, seW1[64 + k], seb1[k])), 0.f);

    float o1[64];
#pragma unroll
    for (int j = 0; j < 64; ++j) o1[j] = b2f[j];
#pragma unroll 4
    for (int k = 0; k < 32; ++k) {
#pragma unroll
        for (int j = 0; j < 64; ++j)
            o1[j] = fmaf(hid[k], M2[k * 64 + j], o1[j]);
    }
    const float* hr = hbuf + (size_t)n * 64;
#pragma unroll 2
    for (int c = 0; c < 16; ++c) {
        float4 hv = *reinterpret_cast<const float4*>(hr + c * 4);
        const float* wb = oW1 + c * 4 * 64;
#pragma unroll
        for (int j = 0; j < 64; ++j) {
            o1[j] = fmaf(hv.x, wb[j], o1[j]);
            o1[j] = fmaf(hv.y, wb[64 + j], o1[j]);
            o1[j] = fmaf(hv.z, wb[128 + j], o1[j]);
            o1[j] = fmaf(hv.w, wb[192 + j], o1[j]);
        }
    }
#pragma unroll
    for (int j = 0; j < 64; ++j) o1[j] = fmaxf(o1[j], 0.f);

    float o2[32];
#pragma unroll
    for (int k = 0; k < 32; ++k) o2[k] = ob2[k];
#pragma unroll 4
    for (int j = 0; j < 64; ++j) {
#pragma unroll
        for (int k = 0; k < 32; ++k)
            o2[k] = fmaf(o1[j], oW2[j * 32 + k], o2[k]);
    }
    float a0 = 0, a1 = 0, a2 = 0, a3 = 0;
#pragma unroll
    for (int k = 0; k < 32; k += 4) {
        a0 = fmaf(fmaxf(o2[k], 0.f), oW3[k], a0);
        a1 = fmaf(fmaxf(o2[k + 1], 0.f), oW3[k + 1], a1);
        a2 = fmaf(fmaxf(o2[k + 2], 0.f), oW3[k + 2], a2);
        a3 = fmaf(fmaxf(o2[k + 3], 0.f), oW3[k + 3], a3);
    }
    if (tid < N)
        out[tid] = 1.f / (1.f + __expf(-((a0 + a1) + (a2 + a3) + ob3[0])));
}

// ---------------- launch ----------------
extern "C" void kernel_launch(void* const* d_in, const int* in_sizes, int n_in,
                              void* d_out, int out_size, void* d_ws, size_t ws_size,
                              hipStream_t stream) {
    const float* x     = (const float*)d_in[0];
    const int*   ei    = (const int*)d_in[1];
    const float* faW1  = (const float*)d_in[2];
    const float* fab1  = (const float*)d_in[3];
    const float* faW2  = (const float*)d_in[4];
    const float* fab2  = (const float*)d_in[5];
    const float* projW = (const float*)d_in[6];
    const float* projb = (const float*)d_in[7];
    const float* gatW  = (const float*)d_in[8];
    const float* gatAs = (const float*)d_in[9];
    const float* gatAd = (const float*)d_in[10];
    const float* gatB  = (const float*)d_in[11];
    const float* bnG   = (const float*)d_in[12];
    const float* bnB   = (const float*)d_in[13];
    const float* bnM   = (const float*)d_in[14];
    const float* bnV   = (const float*)d_in[15];
    const float* seW1  = (const float*)d_in[16];
    const float* seb1  = (const float*)d_in[17];
    const float* seW2  = (const float*)d_in[18];
    const float* seb2  = (const float*)d_in[19];
    const float* oW1   = (const float*)d_in[20];
    const float* ob1   = (const float*)d_in[21];
    const float* oW2   = (const float*)d_in[22];
    const float* ob2   = (const float*)d_in[23];
    const float* oW3   = (const float*)d_in[24];
    const float* ob3   = (const float*)d_in[25];
    float* out = (float*)d_out;

    const int N    = in_sizes[0] / 128;
    const int E    = in_sizes[1] / 2;
    const int Etot = E + N;

    float* ws      = (float*)d_ws;
    float* hbuf    = ws;
    float* zbuf    = hbuf + (size_t)N * 64;
    float* es      = zbuf + (size_t)N * 64;
    float* ed      = es + N;
    // ---- zero region (one memset) ----
    float* deg     = ed + N;
    float* inflsum = deg + N;
    unsigned* scal = (unsigned*)(inflsum + N);     // 8 slots
    int* cnt       = (int*)(scal + 8);
    int* cursor    = cnt + N;
    int* gcur      = cursor + N;                   // 8 slots
    // ---- end zero region ----
    int* startp    = gcur + 8;
    float* inflv   = (float*)(startp + N);
    int* esrc      = (int*)(inflv + N);            // Etot ints
    float* M2      = (float*)(esrc + Etot);        // 32*64
    float* b2f     = M2 + 32 * 64;                 // 64

    dim3 blk(256);
    int gN    = (N + 255) / 256;
    int gE    = (E + 255) / 256;
    int blkNW = (N * 64 + 255) / 256;              // wave-per-node (k_agg)

    hipMemsetAsync(deg, 0, ((size_t)4 * N + 16) * sizeof(float), stream);

    // stage 1: mlp || (deg,cnt) || prep
    k_fused1<<<gN + gE + 1, blk, 0, stream>>>(x, faW1, fab1, faW2, fab2, projW, projb,
                                              hbuf, N, ei, E, deg, cnt,
                                              seW2, seb2, oW1, ob1, M2, b2f, gN, gE);
    // stage 2: inflsum || alloc(+self-loop)
    k_fused2<<<gE + gN, blk, 0, stream>>>(ei, E, deg, inflsum, cnt, startp, esrc, gcur, N, gE);
    // stage 3: fill || infl
    k_fused3<<<gE + gN, blk, 0, stream>>>(ei, E, startp, cursor, esrc,
                                          deg, inflsum, inflv, scal, N, gE);

    for (int l = 0; l < 3; ++l) {
        k_z<<<gN, blk, 0, stream>>>(hbuf, gatW + l * 4096, gatAs + l * 64, gatAd + l * 64,
                                    zbuf, es, ed, N);
        k_agg<<<blkNW, blk, 0, stream>>>(startp, cnt, esrc, es, ed, zbuf,
                                         gatB + l * 64, bnG + l * 64, bnB + l * 64,
                                         bnM + l * 64, bnV + l * 64, hbuf, N);
    }

    k_final<<<gN, blk, 0, stream>>>(hbuf, deg, inflv, scal, seW1, seb1, M2, b2f,
                                    oW1, oW2, ob2, oW3, ob3, out, N);
}

// Round 8
// 880.089 us; speedup vs baseline: 6.3669x; 1.1132x over previous
//
#include <hip/hip_runtime.h>

// r8: bf16 zbuf + dual-edge half-wave k_agg (gather bytes/edge 256->128,
// loop trips halved); inflsum fused into CSR-fill edge pass; infl/scal
// reduction rides on first k_z dispatch.

typedef unsigned int uint;

__device__ __forceinline__ uint f2bf(float a) {     // RNE f32->bf16 (finite)
    uint u = __float_as_uint(a);
    return (u + 0x7fffu + ((u >> 16) & 1u)) >> 16;
}

// ---------------- fused stage 1: node MLP || deg/cnt histograms || prep ------
__global__ __attribute__((amdgpu_waves_per_eu(3, 3))) void __launch_bounds__(256)
k_fused1(const float* __restrict__ x,
         const float* __restrict__ faW1, const float* __restrict__ fab1,
         const float* __restrict__ faW2, const float* __restrict__ fab2,
         const float* __restrict__ projW, const float* __restrict__ projb,
         float* __restrict__ hbuf, int N,
         const int* __restrict__ ei, int E,
         float* __restrict__ deg, int* __restrict__ cnt,
         const float* __restrict__ seW2, const float* __restrict__ seb2,
         const float* __restrict__ oW1, const float* __restrict__ ob1,
         float* __restrict__ M2, float* __restrict__ b2f,
         int gMlp, int gEdge) {
    int bid = blockIdx.x;
    if (bid < gMlp) {
        int tid = bid * blockDim.x + threadIdx.x;
        int n = tid < N ? tid : N - 1;
        const float* xr = x + (size_t)n * 128;

        float t[64];
#pragma unroll
        for (int j = 0; j < 64; ++j) t[j] = fab1[j];
#pragma unroll 2
        for (int c = 0; c < 32; ++c) {
            float4 xv = *reinterpret_cast<const float4*>(xr + c * 4);
            const float* wb = faW1 + c * 4 * 64;
#pragma unroll
            for (int j = 0; j < 64; ++j) {
                t[j] = fmaf(xv.x, wb[j], t[j]);
                t[j] = fmaf(xv.y, wb[64 + j], t[j]);
                t[j] = fmaf(xv.z, wb[128 + j], t[j]);
                t[j] = fmaf(xv.w, wb[192 + j], t[j]);
            }
        }
#pragma unroll
        for (int j = 0; j < 64; ++j) t[j] = fmaxf(t[j], 0.f);

        float h[64];
#pragma unroll
        for (int j = 0; j < 64; ++j) h[j] = projb[j];
#pragma unroll 2
        for (int c = 0; c < 32; ++c) {
            float4 xv = *reinterpret_cast<const float4*>(xr + c * 4);
            int i0 = c * 4;
            float f0 = fab2[i0], f1 = fab2[i0 + 1], f2 = fab2[i0 + 2], f3 = fab2[i0 + 3];
            const float* w2 = faW2 + i0;
#pragma unroll
            for (int j = 0; j < 64; ++j) {
                float tj = t[j];
                f0 = fmaf(tj, w2[j * 128], f0);
                f1 = fmaf(tj, w2[j * 128 + 1], f1);
                f2 = fmaf(tj, w2[j * 128 + 2], f2);
                f3 = fmaf(tj, w2[j * 128 + 3], f3);
            }
            float xm0 = xv.x / (1.f + __expf(-f0));
            float xm1 = xv.y / (1.f + __expf(-f1));
            float xm2 = xv.z / (1.f + __expf(-f2));
            float xm3 = xv.w / (1.f + __expf(-f3));
            const float* wp = projW + i0 * 64;
#pragma unroll
            for (int j = 0; j < 64; ++j) {
                h[j] = fmaf(xm0, wp[j], h[j]);
                h[j] = fmaf(xm1, wp[64 + j], h[j]);
                h[j] = fmaf(xm2, wp[128 + j], h[j]);
                h[j] = fmaf(xm3, wp[192 + j], h[j]);
            }
        }
        if (tid < N) {
            float* hr = hbuf + (size_t)tid * 64;
#pragma unroll
            for (int c = 0; c < 16; ++c)
                *reinterpret_cast<float4*>(hr + c * 4) =
                    make_float4(h[c * 4], h[c * 4 + 1], h[c * 4 + 2], h[c * 4 + 3]);
        }
    } else if (bid < gMlp + gEdge) {
        int e = (bid - gMlp) * blockDim.x + threadIdx.x;
        if (e < E) {
            atomicAdd(&deg[ei[e]], 1.f);
            atomicAdd(&cnt[ei[E + e]], 1);
        }
    } else {
        int tid = threadIdx.x;
        for (int o = tid; o < 32 * 64; o += 256) {
            int k = o >> 6, j = o & 63;
            float s = 0.f;
            for (int i = 0; i < 64; ++i)
                s = fmaf(seW2[k * 64 + i], oW1[(64 + i) * 64 + j], s);
            M2[o] = s;
        }
        for (int j = tid; j < 64; j += 256) {
            float s = ob1[j];
            for (int i = 0; i < 64; ++i)
                s = fmaf(seb2[i], oW1[(64 + i) * 64 + j], s);
            b2f[j] = s;
        }
    }
}

// ---------------- CSR alloc (+self-loop at slot 0) ----------------
__global__ void k_alloc(const int* __restrict__ cnt, int* __restrict__ startp,
                        int* __restrict__ esrc, int* __restrict__ gcur, int N) {
    int idx  = blockIdx.x * blockDim.x + threadIdx.x;
    int lane = threadIdx.x & 63;
    int c = idx < N ? cnt[idx] + 1 : 0;
    int sc = c;
#pragma unroll
    for (int off = 1; off < 64; off <<= 1) {
        int t = __shfl_up(sc, off, 64);
        if (lane >= off) sc += t;
    }
    int base = 0;
    if (lane == 63) base = atomicAdd(gcur, sc);
    base = __shfl(base, 63, 64);
    if (idx < N) {
        int st = base + sc - c;
        startp[idx] = st;
        esrc[st] = idx;                    // self-loop at slot 0
    }
}

// ---------------- CSR fill + inflsum (one edge pass) ----------------
__global__ void k_fill(const int* __restrict__ ei, int E,
                       const int* __restrict__ startp, int* __restrict__ cursor,
                       int* __restrict__ esrc,
                       const float* __restrict__ deg, float* __restrict__ inflsum) {
    int e = blockIdx.x * blockDim.x + threadIdx.x;
    if (e >= E) return;
    int s = ei[e], d = ei[E + e];
    int p = atomicAdd(&cursor[d], 1);
    esrc[startp[d] + 1 + p] = s;
    atomicAdd(&inflsum[s], deg[d]);
}

// ---------------- GAT: z = h@W (bf16 out), es/ed; || infl reduce -------------
__global__ __attribute__((amdgpu_waves_per_eu(4, 4))) void __launch_bounds__(256)
k_z(const float* __restrict__ hbuf, const float* __restrict__ W,
    const float* __restrict__ asrc, const float* __restrict__ adst,
    uint* __restrict__ zbuf, float* __restrict__ es, float* __restrict__ ed,
    const float* __restrict__ deg, const float* __restrict__ inflsum,
    float* __restrict__ inflv, unsigned* __restrict__ scal,
    int N, int gN) {
    int bid = blockIdx.x;
    if (bid >= gN) {
        // ---- structural infl + global maxes (first layer only) ----
        int idx = (bid - gN) * blockDim.x + threadIdx.x;
        float dv = 0.f, iv = 0.f;
        if (idx < N) {
            dv = deg[idx];
            iv = dv > 0.f ? inflsum[idx] / dv : 0.f;
            inflv[idx] = iv;
        }
        float dm = dv, im = iv;
#pragma unroll
        for (int off = 32; off; off >>= 1) {
            dm = fmaxf(dm, __shfl_xor(dm, off, 64));
            im = fmaxf(im, __shfl_xor(im, off, 64));
        }
        if ((threadIdx.x & 63) == 0) {
            atomicMax(scal + 0, __float_as_uint(dm));
            atomicMax(scal + 1, __float_as_uint(im));
        }
        return;
    }
    int tid = bid * blockDim.x + threadIdx.x;
    int n = tid < N ? tid : N - 1;
    const float* hr = hbuf + (size_t)n * 64;
    float z[64];
#pragma unroll
    for (int j = 0; j < 64; ++j) z[j] = 0.f;
#pragma unroll 2
    for (int c = 0; c < 16; ++c) {
        float4 hv = *reinterpret_cast<const float4*>(hr + c * 4);
        const float* wb = W + c * 4 * 64;
#pragma unroll
        for (int j = 0; j < 64; ++j) {
            z[j] = fmaf(hv.x, wb[j], z[j]);
            z[j] = fmaf(hv.y, wb[64 + j], z[j]);
            z[j] = fmaf(hv.z, wb[128 + j], z[j]);
            z[j] = fmaf(hv.w, wb[192 + j], z[j]);
        }
    }
    float e0 = 0, e1 = 0, e2 = 0, e3 = 0, d0 = 0, d1 = 0, d2 = 0, d3 = 0;
#pragma unroll
    for (int j = 0; j < 64; j += 4) {
        e0 = fmaf(z[j], asrc[j], e0);
        e1 = fmaf(z[j + 1], asrc[j + 1], e1);
        e2 = fmaf(z[j + 2], asrc[j + 2], e2);
        e3 = fmaf(z[j + 3], asrc[j + 3], e3);
        d0 = fmaf(z[j], adst[j], d0);
        d1 = fmaf(z[j + 1], adst[j + 1], d1);
        d2 = fmaf(z[j + 2], adst[j + 2], d2);
        d3 = fmaf(z[j + 3], adst[j + 3], d3);
    }
    if (tid < N) {
        uint* zr = zbuf + (size_t)tid * 32;
#pragma unroll
        for (int c = 0; c < 8; ++c) {
            uint4 pv;
            pv.x = f2bf(z[c * 8 + 0]) | (f2bf(z[c * 8 + 1]) << 16);
            pv.y = f2bf(z[c * 8 + 2]) | (f2bf(z[c * 8 + 3]) << 16);
            pv.z = f2bf(z[c * 8 + 4]) | (f2bf(z[c * 8 + 5]) << 16);
            pv.w = f2bf(z[c * 8 + 6]) | (f2bf(z[c * 8 + 7]) << 16);
            *reinterpret_cast<uint4*>(zr + c * 4) = pv;
        }
        es[tid] = (e0 + e1) + (e2 + e3);
        ed[tid] = (d0 + d1) + (d2 + d3);
    }
}

// ---------------- fused GAT aggregation: dual-edge half-wave ----------------
// Wave per dst node. Lane holds 2 features (u32 = 2 bf16); lanes 0-31 process
// even CSR slots, 32-63 odd slots; shfl_xor(32) combines. exp weights cached
// in one register per lane (slot = lane), broadcast via bpermute.
__global__ void k_agg(const int* __restrict__ start, const int* __restrict__ cnt,
                      const int* __restrict__ esrc,
                      const float* __restrict__ es, const float* __restrict__ ed,
                      const uint* __restrict__ zb,
                      const float* __restrict__ b, const float* __restrict__ g,
                      const float* __restrict__ bta, const float* __restrict__ mean,
                      const float* __restrict__ var,
                      float* __restrict__ hbuf, int N) {
    int wid  = (blockIdx.x * blockDim.x + threadIdx.x) >> 6;
    int lane = threadIdx.x & 63;
    if (wid >= N) return;
    int row0 = start[wid];
    int c    = cnt[wid] + 1;       // +1 self-loop
    float edn = ed[wid];
    int lk = lane & 31, half = lane >> 5;

    int   sreg = 0;
    float exv  = 0.f;
    if (lane < c) {
        sreg = esrc[row0 + lane];
        float e = es[sreg] + edn;
        e = e >= 0.f ? e : 0.2f * e;
        exv = __expf(e);
    }
    float ssum = exv;
    for (int k = 64 + lane; k < c; k += 64) {          // rare tail c>64
        int s = esrc[row0 + k];
        float e = es[s] + edn; e = e >= 0.f ? e : 0.2f * e;
        ssum += __expf(e);
    }
#pragma unroll
    for (int off = 32; off; off >>= 1) ssum += __shfl_xor(ssum, off, 64);

    float acc0 = 0.f, acc1 = 0.f;
    int kmax = c < 64 ? c : 64;
    for (int e = half; e < kmax; e += 2) {
        int   se = __shfl(sreg, e, 64);
        float we = __shfl(exv, e, 64);
        uint p = zb[(size_t)se * 32 + lk];
        acc0 = fmaf(__uint_as_float(p << 16), we, acc0);
        acc1 = fmaf(__uint_as_float(p & 0xffff0000u), we, acc1);
    }
    for (int e = 64; e < c; ++e) {                     // rare tail c>64
        int s = esrc[row0 + e];
        float ee = es[s] + edn; ee = ee >= 0.f ? ee : 0.2f * ee;
        float we = __expf(ee);
        if (half == 0) {
            uint p = zb[(size_t)s * 32 + lk];
            acc0 = fmaf(__uint_as_float(p << 16), we, acc0);
            acc1 = fmaf(__uint_as_float(p & 0xffff0000u), we, acc1);
        }
    }
    acc0 += __shfl_xor(acc0, 32, 64);
    acc1 += __shfl_xor(acc1, 32, 64);

    if (half == 0) {
        float inv = 1.f / ssum;
        float2 bb = reinterpret_cast<const float2*>(b)[lk];
        float2 gg = reinterpret_cast<const float2*>(g)[lk];
        float2 tt = reinterpret_cast<const float2*>(bta)[lk];
        float2 mm = reinterpret_cast<const float2*>(mean)[lk];
        float2 vv = reinterpret_cast<const float2*>(var)[lk];
        float v0 = (acc0 * inv + bb.x - mm.x) * (gg.x * rsqrtf(vv.x + 1e-5f)) + tt.x;
        float v1 = (acc1 * inv + bb.y - mm.y) * (gg.y * rsqrtf(vv.y + 1e-5f)) + tt.y;
        reinterpret_cast<float2*>(hbuf + (size_t)wid * 64)[lk] =
            make_float2(fmaxf(v0, 0.f), fmaxf(v1, 0.f));
    }
}

// ---------------- output head: lane = node ----------------
__global__ __attribute__((amdgpu_waves_per_eu(4, 4))) void __launch_bounds__(256)
k_final(const float* __restrict__ hbuf, const float* __restrict__ deg,
        const float* __restrict__ inflv, const unsigned* __restrict__ scal,
        const float* __restrict__ seW1, const float* __restrict__ seb1,
        const float* __restrict__ M2, const float* __restrict__ b2f,
        const float* __restrict__ oW1,
        const float* __restrict__ oW2, const float* __restrict__ ob2,
        const float* __restrict__ oW3, const float* __restrict__ ob3,
        float* __restrict__ out, int N) {
    int tid = blockIdx.x * blockDim.x + threadIdx.x;
    int n = tid < N ? tid : N - 1;

    float degmax  = fmaxf(__uint_as_float(scal[0]), 1.0f);
    float inflmax = fmaxf(__uint_as_float(scal[1]), 1e-12f);
    float nd = deg[n] / degmax;
    float fl = inflv[n] / inflmax;

    float hid[32];
#pragma unroll
    for (int k = 0; k < 32; ++k)
        hid[k] = fmaxf(fmaf(nd, seW1[k], fmaf(fl, seW1[64 + k], seb1[k])), 0.f);

    float o1[64];
#pragma unroll
    for (int j = 0; j < 64; ++j) o1[j] = b2f[j];
#pragma unroll 4
    for (int k = 0; k < 32; ++k) {
#pragma unroll
        for (int j = 0; j < 64; ++j)
            o1[j] = fmaf(hid[k], M2[k * 64 + j], o1[j]);
    }
    const float* hr = hbuf + (size_t)n * 64;
#pragma unroll 2
    for (int c = 0; c < 16; ++c) {
        float4 hv = *reinterpret_cast<const float4*>(hr + c * 4);
        const float* wb = oW1 + c * 4 * 64;
#pragma unroll
        for (int j = 0; j < 64; ++j) {
            o1[j] = fmaf(hv.x, wb[j], o1[j]);
            o1[j] = fmaf(hv.y, wb[64 + j], o1[j]);
            o1[j] = fmaf(hv.z, wb[128 + j], o1[j]);
            o1[j] = fmaf(hv.w, wb[192 + j], o1[j]);
        }
    }
#pragma unroll
    for (int j = 0; j < 64; ++j) o1[j] = fmaxf(o1[j], 0.f);

    float o2[32];
#pragma unroll
    for (int k = 0; k < 32; ++k) o2[k] = ob2[k];
#pragma unroll 4
    for (int j = 0; j < 64; ++j) {
#pragma unroll
        for (int k = 0; k < 32; ++k)
            o2[k] = fmaf(o1[j], oW2[j * 32 + k], o2[k]);
    }
    float a0 = 0, a1 = 0, a2 = 0, a3 = 0;
#pragma unroll
    for (int k = 0; k < 32; k += 4) {
        a0 = fmaf(fmaxf(o2[k], 0.f), oW3[k], a0);
        a1 = fmaf(fmaxf(o2[k + 1], 0.f), oW3[k + 1], a1);
        a2 = fmaf(fmaxf(o2[k + 2], 0.f), oW3[k + 2], a2);
        a3 = fmaf(fmaxf(o2[k + 3], 0.f), oW3[k + 3], a3);
    }
    if (tid < N)
        out[tid] = 1.f / (1.f + __expf(-((a0 + a1) + (a2 + a3) + ob3[0])));
}

// ---------------- launch ----------------
extern "C" void kernel_launch(void* const* d_in, const int* in_sizes, int n_in,
                              void* d_out, int out_size, void* d_ws, size_t ws_size,
                              hipStream_t stream) {
    const float* x     = (const float*)d_in[0];
    const int*   ei    = (const int*)d_in[1];
    const float* faW1  = (const float*)d_in[2];
    const float* fab1  = (const float*)d_in[3];
    const float* faW2  = (const float*)d_in[4];
    const float* fab2  = (const float*)d_in[5];
    const float* projW = (const float*)d_in[6];
    const float* projb = (const float*)d_in[7];
    const float* gatW  = (const float*)d_in[8];
    const float* gatAs = (const float*)d_in[9];
    const float* gatAd = (const float*)d_in[10];
    const float* gatB  = (const float*)d_in[11];
    const float* bnG   = (const float*)d_in[12];
    const float* bnB   = (const float*)d_in[13];
    const float* bnM   = (const float*)d_in[14];
    const float* bnV   = (const float*)d_in[15];
    const float* seW1  = (const float*)d_in[16];
    const float* seb1  = (const float*)d_in[17];
    const float* seW2  = (const float*)d_in[18];
    const float* seb2  = (const float*)d_in[19];
    const float* oW1   = (const float*)d_in[20];
    const float* ob1   = (const float*)d_in[21];
    const float* oW2   = (const float*)d_in[22];
    const float* ob2   = (const float*)d_in[23];
    const float* oW3   = (const float*)d_in[24];
    const float* ob3   = (const float*)d_in[25];
    float* out = (float*)d_out;

    const int N    = in_sizes[0] / 128;
    const int E    = in_sizes[1] / 2;
    const int Etot = E + N;

    float* ws      = (float*)d_ws;
    float* hbuf    = ws;
    uint*  zbuf    = (uint*)(hbuf + (size_t)N * 64);   // N*32 uints (bf16 pairs)
    float* es      = (float*)(zbuf + (size_t)N * 64);  // region kept N*64 wide
    float* ed      = es + N;
    // ---- zero region (one memset) ----
    float* deg     = ed + N;
    float* inflsum = deg + N;
    unsigned* scal = (unsigned*)(inflsum + N);     // 8 slots
    int* cnt       = (int*)(scal + 8);
    int* cursor    = cnt + N;
    int* gcur      = cursor + N;                   // 8 slots
    // ---- end zero region ----
    int* startp    = gcur + 8;
    float* inflv   = (float*)(startp + N);
    int* esrc      = (int*)(inflv + N);            // Etot ints
    float* M2      = (float*)(esrc + Etot);        // 32*64
    float* b2f     = M2 + 32 * 64;                 // 64

    dim3 blk(256);
    int gN    = (N + 255) / 256;
    int gE    = (E + 255) / 256;
    int blkNW = (N * 64 + 255) / 256;              // wave-per-node (k_agg)

    hipMemsetAsync(deg, 0, ((size_t)4 * N + 16) * sizeof(float), stream);

    // stage 1: mlp || (deg,cnt) || prep
    k_fused1<<<gN + gE + 1, blk, 0, stream>>>(x, faW1, fab1, faW2, fab2, projW, projb,
                                              hbuf, N, ei, E, deg, cnt,
                                              seW2, seb2, oW1, ob1, M2, b2f, gN, gE);
    // stage 2: CSR alloc (+self-loop)
    k_alloc<<<gN, blk, 0, stream>>>(cnt, startp, esrc, gcur, N);
    // stage 3: CSR fill + inflsum (one edge pass)
    k_fill<<<gE, blk, 0, stream>>>(ei, E, startp, cursor, esrc, deg, inflsum);

    for (int l = 0; l < 3; ++l) {
        int extra = (l == 0) ? gN : 0;             // infl/scal reduce rides on first k_z
        k_z<<<gN + extra, blk, 0, stream>>>(hbuf, gatW + l * 4096, gatAs + l * 64,
                                            gatAd + l * 64, zbuf, es, ed,
                                            deg, inflsum, inflv, scal, N, gN);
        k_agg<<<blkNW, blk, 0, stream>>>(startp, cnt, esrc, es, ed, zbuf,
                                         gatB + l * 64, bnG + l * 64, bnB + l * 64,
                                         bnM + l * 64, bnV + l * 64, hbuf, N);
    }

    k_final<<<gN, blk, 0, stream>>>(hbuf, deg, inflv, scal, seW1, seb1, M2, b2f,
                                    oW1, oW2, ob2, oW3, ob3, out, N);
}